// Round 1
// baseline (488.081 us; speedup 1.0000x reference)
//
#include <hip/hip_runtime.h>
#include <math.h>

#define S_LEN 1024
#define QKV_N 5120

typedef __attribute__((ext_vector_type(8))) __bf16 bf16x8;
typedef __attribute__((ext_vector_type(4))) float f32x4;

__device__ __forceinline__ unsigned short f2bf(float f) {
  unsigned int u = __float_as_uint(f);
  u += 0x7fff + ((u >> 16) & 1);
  return (unsigned short)(u >> 16);
}

__device__ __forceinline__ void async_copy16(const void* g, void* l) {
  __builtin_amdgcn_global_load_lds(
      (const __attribute__((address_space(1))) unsigned int*)g,
      (__attribute__((address_space(3))) unsigned int*)l, 16, 0, 0);
}

// ---------------- fp32 -> bf16 convert (vectorized x4) ----------------
__global__ void cvt_bf16(const float* __restrict__ in, unsigned short* __restrict__ out, int n4) {
  int i = blockIdx.x * 256 + threadIdx.x;
  if (i >= n4) return;
  float4 v = ((const float4*)in)[i];
  ushort4 r;
  r.x = f2bf(v.x); r.y = f2bf(v.y); r.z = f2bf(v.z); r.w = f2bf(v.w);
  ((ushort4*)out)[i] = r;
}

__global__ void concat_bias(const float* __restrict__ bq, const float* __restrict__ bk,
                            const float* __restrict__ bv, float* __restrict__ o) {
  int i = blockIdx.x * 256 + threadIdx.x;
  if (i >= 5120) return;
  o[i] = (i < 4096) ? bq[i] : ((i < 4608) ? bk[i - 4096] : bv[i - 4608]);
}

// ---------------- YaRN rope tables: cos/sin [S][32] ----------------
__global__ void rope_tables(const int* __restrict__ positions, float* __restrict__ cosT,
                            float* __restrict__ sinT, float low, float high, float mscale) {
  int idx = blockIdx.x * 256 + threadIdx.x;  // S*32
  if (idx >= S_LEN * 32) return;
  int j = idx & 31, s = idx >> 5;
  float pf = powf(150000.0f, (float)j / 32.0f);
  float ramp = ((float)j - low) / (high - low);
  ramp = fminf(fmaxf(ramp, 0.0f), 1.0f);
  float invf = (1.0f / (32.0f * pf)) * ramp + (1.0f / pf) * (1.0f - ramp);
  float ang = (float)positions[s] * invf;
  cosT[idx] = cosf(ang) * mscale;
  sinT[idx] = sinf(ang) * mscale;
}

// ---------------- in-place rope on qkv cols [0,4608) ----------------
// cols 0..4607 are 72 heads (64 q + 8 k) of 64 contiguous elements each.
__global__ void rope_kernel(float* __restrict__ qkv, const float* __restrict__ cosT,
                            const float* __restrict__ sinT) {
  int idx = blockIdx.x * 256 + threadIdx.x;  // S*72*32
  if (idx >= S_LEN * 72 * 32) return;
  int j = idx & 31;
  int hh = (idx >> 5) % 72;
  int s = idx / (72 * 32);
  float* base = qkv + (size_t)s * QKV_N + hh * 64;
  float x = base[j], y = base[j + 32];
  float c = cosT[s * 32 + j], sn = sinT[s * 32 + j];
  base[j]      = x * c - y * sn;
  base[j + 32] = y * c + x * sn;
}

// ---------------- NT bf16 MFMA GEMM: C[M][N] = A[M][K] * B[N][K]^T + bias ----------------
// m97 structure: 128x128 tile, BK=32, 4 waves, 4x4 16x16x32 MFMAs per wave.
__global__ __launch_bounds__(256) void gemm_bt(
    const unsigned short* __restrict__ A, const unsigned short* __restrict__ B,
    const float* __restrict__ bias, float* __restrict__ C, int M, int N, int K) {
  __shared__ __align__(16) unsigned short As[128 * 32];
  __shared__ __align__(16) unsigned short Bs[128 * 32];
  const int t = threadIdx.x;
  const int l = t & 63;
  const int w = t >> 6;
  const int lr = l & 15, lq = l >> 4;
  const int m0 = blockIdx.y * 128, n0 = blockIdx.x * 128;
  const int wm = (w >> 1) * 64, wn = (w & 1) * 64;

  const int rowA = t >> 2;       // 0..63
  const int kg = (t & 3) * 8;    // k-group offset in elements

  int rb0 = n0 + rowA;      if (rb0 > N - 1) rb0 = N - 1;
  int rb1 = n0 + rowA + 64; if (rb1 > N - 1) rb1 = N - 1;

  const unsigned short* gA0 = A + (size_t)(m0 + rowA) * K + kg;
  const unsigned short* gA1 = gA0 + (size_t)64 * K;
  const unsigned short* gB0 = B + (size_t)rb0 * K + kg;
  const unsigned short* gB1 = B + (size_t)rb1 * K + kg;

  unsigned short* lA0 = &As[t * 8];
  unsigned short* lA1 = &As[(t + 256) * 8];
  unsigned short* lB0 = &Bs[t * 8];
  unsigned short* lB1 = &Bs[(t + 256) * 8];

  f32x4 acc[4][4] = {};

  for (int k0 = 0; k0 < K; k0 += 32) {
    async_copy16(gA0 + k0, lA0);
    async_copy16(gA1 + k0, lA1);
    async_copy16(gB0 + k0, lB0);
    async_copy16(gB1 + k0, lB1);
    __syncthreads();  // drains vmcnt -> LDS tiles ready
    bf16x8 af[4], bf[4];
#pragma unroll
    for (int i = 0; i < 4; i++)
      af[i] = *(const bf16x8*)&As[(wm + i * 16 + lr) * 32 + lq * 8];
#pragma unroll
    for (int i = 0; i < 4; i++)
      bf[i] = *(const bf16x8*)&Bs[(wn + i * 16 + lr) * 32 + lq * 8];
#pragma unroll
    for (int mi = 0; mi < 4; mi++)
#pragma unroll
      for (int ni = 0; ni < 4; ni++)
        acc[mi][ni] = __builtin_amdgcn_mfma_f32_16x16x32_bf16(af[mi], bf[ni], acc[mi][ni], 0, 0, 0);
    __syncthreads();  // all waves done reading before next stage
  }

#pragma unroll
  for (int mi = 0; mi < 4; mi++) {
#pragma unroll
    for (int ni = 0; ni < 4; ni++) {
      int col = n0 + wn + ni * 16 + lr;
      if (col < N) {
        float bv = bias[col];
#pragma unroll
        for (int r = 0; r < 4; r++) {
          int row = m0 + wm + mi * 16 + lq * 4 + r;
          C[(size_t)row * N + col] = acc[mi][ni][r] + bv;
        }
      }
    }
  }
}

// ---------------- sliding-window attention with sinks ----------------
// block = (head h, 16 queries). 16 lanes per query, 4 d-elems per lane.
__global__ __launch_bounds__(256) void attn_kernel(
    const float* __restrict__ qkv, const float* __restrict__ sinks,
    unsigned short* __restrict__ out) {
  const int h = blockIdx.x;   // 0..63
  const int qt = blockIdx.y;  // 0..63
  const int t = threadIdx.x;
  const int ql = t >> 4, sub = t & 15;
  const int q = qt * 16 + ql;
  const int kvh = h >> 3;

  float4 qv = *(const float4*)(qkv + (size_t)q * QKV_N + h * 64 + sub * 4);
  const float sc = 0.125f;  // D^-0.5
  qv.x *= sc; qv.y *= sc; qv.z *= sc; qv.w *= sc;

  int w0 = q - 127; if (w0 < 0) w0 = 0;
  const int nk = q - w0 + 1;

  float m = -3.0e38f, lsum = 0.0f;
  float4 o = {0.0f, 0.0f, 0.0f, 0.0f};
  const float* kbase = qkv + 4096 + kvh * 64 + sub * 4;

  for (int i = 0; i < nk; i++) {
    const float* kr = kbase + (size_t)(w0 + i) * QKV_N;
    float4 kk = *(const float4*)kr;
    float d = qv.x * kk.x + qv.y * kk.y + qv.z * kk.z + qv.w * kk.w;
    d += __shfl_xor(d, 1);
    d += __shfl_xor(d, 2);
    d += __shfl_xor(d, 4);
    d += __shfl_xor(d, 8);
    float mn = fmaxf(m, d);
    float corr = __expf(m - mn);
    float p = __expf(d - mn);
    float4 vv = *(const float4*)(kr + 512);
    o.x = o.x * corr + p * vv.x;
    o.y = o.y * corr + p * vv.y;
    o.z = o.z * corr + p * vv.z;
    o.w = o.w * corr + p * vv.w;
    lsum = lsum * corr + p;
    m = mn;
  }

  float sink = sinks[h];
  float mn2 = fmaxf(m, sink);
  float corr = __expf(m - mn2);
  float denom = lsum * corr + __expf(sink - mn2);
  float fs = corr / denom;

  ushort4 r;
  r.x = f2bf(o.x * fs); r.y = f2bf(o.y * fs); r.z = f2bf(o.z * fs); r.w = f2bf(o.w * fs);
  *(ushort4*)(out + (size_t)q * 4096 + h * 64 + sub * 4) = r;
}

extern "C" void kernel_launch(void* const* d_in, const int* in_sizes, int n_in,
                              void* d_out, int out_size, void* d_ws, size_t ws_size,
                              hipStream_t stream) {
  const float* x = (const float*)d_in[0];
  const int* positions = (const int*)d_in[1];
  const float* Wq = (const float*)d_in[2];
  const float* bq = (const float*)d_in[3];
  const float* Wk = (const float*)d_in[4];
  const float* bk = (const float*)d_in[5];
  const float* Wv = (const float*)d_in[6];
  const float* bv = (const float*)d_in[7];
  const float* Wo = (const float*)d_in[8];
  const float* bo = (const float*)d_in[9];
  const float* sinks = (const float*)d_in[10];
  float* out = (float*)d_out;

  char* ws = (char*)d_ws;
  unsigned short* xb   = (unsigned short*)(ws + 0);           // 1024x2880 bf16
  unsigned short* wqkv = (unsigned short*)(ws + 5898240);     // 5120x2880 bf16
  unsigned short* wo   = (unsigned short*)(ws + 35389440);    // 2880x4096 bf16
  float* bqkv          = (float*)(ws + 58982400);             // 5120 f32
  float* qkv           = (float*)(ws + 59002880);             // 1024x5120 f32
  float* cosT          = (float*)(ws + 79974400);             // 1024x32 f32
  float* sinT          = (float*)(ws + 80105472);             // 1024x32 f32
  unsigned short* attnb = (unsigned short*)(ws + 80236544);   // 1024x4096 bf16

  cvt_bf16<<<2880, 256, 0, stream>>>(x, xb, 737280);
  cvt_bf16<<<11520, 256, 0, stream>>>(Wq, wqkv, 2949120);
  cvt_bf16<<<1440, 256, 0, stream>>>(Wk, wqkv + (size_t)4096 * 2880, 368640);
  cvt_bf16<<<1440, 256, 0, stream>>>(Wv, wqkv + (size_t)4608 * 2880, 368640);
  cvt_bf16<<<11520, 256, 0, stream>>>(Wo, wo, 2949120);
  concat_bias<<<20, 256, 0, stream>>>(bq, bk, bv, bqkv);

  // YaRN constants (host, double precision)
  const double TWO_PI = 6.283185307179586;
  double lowd = 64.0 * log(4096.0 / (32.0 * TWO_PI)) / (2.0 * log(150000.0));
  if (lowd < 0.0) lowd = 0.0;
  double highd = 64.0 * log(4096.0 / (1.0 * TWO_PI)) / (2.0 * log(150000.0));
  if (highd > 31.0) highd = 31.0;
  if (lowd == highd) highd += 0.001;
  float mscale = (float)(0.1 * log(32.0) + 1.0);
  rope_tables<<<128, 256, 0, stream>>>(positions, cosT, sinT, (float)lowd, (float)highd, mscale);

  // QKV projection: [1024][5120] = x * [Wq;Wk;Wv]^T + b
  gemm_bt<<<dim3(40, 8), 256, 0, stream>>>(xb, wqkv, bqkv, qkv, 1024, 5120, 2880);
  rope_kernel<<<9216, 256, 0, stream>>>(qkv, cosT, sinT);
  attn_kernel<<<dim3(64, 64), 256, 0, stream>>>(qkv, sinks, attnb);
  // Output projection: [1024][2880] = attn * Wo^T + bo
  gemm_bt<<<dim3(23, 8), 256, 0, stream>>>(attnb, wo, bo, out, 1024, 2880, 4096);
}

// Round 2
// 373.382 us; speedup vs baseline: 1.3072x; 1.3072x over previous
//
#include <hip/hip_runtime.h>
#include <math.h>

#define S_LEN 1024
#define QKV_N 5120

typedef __attribute__((ext_vector_type(8))) __bf16 bf16x8;
typedef __attribute__((ext_vector_type(4))) float f32x4;

__device__ __forceinline__ unsigned short f2bf(float f) {
  unsigned int u = __float_as_uint(f);
  u += 0x7fff + ((u >> 16) & 1);
  return (unsigned short)(u >> 16);
}
__device__ __forceinline__ float bf2f(unsigned short u) {
  return __uint_as_float((unsigned int)u << 16);
}

__device__ __forceinline__ void async_copy16(const void* g, void* l) {
  __builtin_amdgcn_global_load_lds(
      (const __attribute__((address_space(1))) unsigned int*)g,
      (__attribute__((address_space(3))) unsigned int*)l, 16, 0, 0);
}

// ---------------- fp32 -> bf16 convert (vectorized x4) ----------------
__global__ void cvt_bf16(const float* __restrict__ in, unsigned short* __restrict__ out, int n4) {
  int i = blockIdx.x * 256 + threadIdx.x;
  if (i >= n4) return;
  float4 v = ((const float4*)in)[i];
  ushort4 r;
  r.x = f2bf(v.x); r.y = f2bf(v.y); r.z = f2bf(v.z); r.w = f2bf(v.w);
  ((ushort4*)out)[i] = r;
}

__global__ void concat_bias(const float* __restrict__ bq, const float* __restrict__ bk,
                            const float* __restrict__ bv, float* __restrict__ o) {
  int i = blockIdx.x * 256 + threadIdx.x;
  if (i >= 5120) return;
  o[i] = (i < 4096) ? bq[i] : ((i < 4608) ? bk[i - 4096] : bv[i - 4608]);
}

// ---------------- YaRN rope tables: cos/sin [S][32] ----------------
__global__ void rope_tables(const int* __restrict__ positions, float* __restrict__ cosT,
                            float* __restrict__ sinT, float low, float high, float mscale) {
  int idx = blockIdx.x * 256 + threadIdx.x;  // S*32
  if (idx >= S_LEN * 32) return;
  int j = idx & 31, s = idx >> 5;
  float pf = powf(150000.0f, (float)j / 32.0f);
  float ramp = ((float)j - low) / (high - low);
  ramp = fminf(fmaxf(ramp, 0.0f), 1.0f);
  float invf = (1.0f / (32.0f * pf)) * ramp + (1.0f / pf) * (1.0f - ramp);
  float ang = (float)positions[s] * invf;
  cosT[idx] = cosf(ang) * mscale;
  sinT[idx] = sinf(ang) * mscale;
}

// ---------------- rope: qkvb (bf16) -> Qb (scaled bf16), Kb (bf16) ----------------
__global__ void rope_kernel(const unsigned short* __restrict__ qkvb,
                            const float* __restrict__ cosT, const float* __restrict__ sinT,
                            unsigned short* __restrict__ Qb, unsigned short* __restrict__ Kb) {
  int idx = blockIdx.x * 256 + threadIdx.x;  // S*72*32
  if (idx >= S_LEN * 72 * 32) return;
  int j = idx & 31;
  int hh = (idx >> 5) % 72;
  int s = idx / (72 * 32);
  const unsigned short* base = qkvb + (size_t)s * QKV_N + hh * 64;
  float x = bf2f(base[j]), y = bf2f(base[j + 32]);
  float c = cosT[s * 32 + j], sn = sinT[s * 32 + j];
  float o1 = x * c - y * sn;
  float o2 = y * c + x * sn;
  if (hh < 64) {
    unsigned short* q = Qb + ((size_t)s * 64 + hh) * 64;
    q[j]      = f2bf(o1 * 0.125f);   // fold in D^-0.5
    q[j + 32] = f2bf(o2 * 0.125f);
  } else {
    unsigned short* k = Kb + ((size_t)s * 8 + (hh - 64)) * 64;
    k[j]      = f2bf(o1);
    k[j + 32] = f2bf(o2);
  }
}

// ---------------- V transpose: qkvb v-cols -> Vt[KV*64 dims][S] bf16 ----------------
__global__ __launch_bounds__(256) void v_transpose(const unsigned short* __restrict__ qkvb,
                                                   unsigned short* __restrict__ Vt) {
  __shared__ unsigned short tile[128][66];  // +2 pad -> odd dword stride, conflict-free
  const int kvh = blockIdx.x, s0 = blockIdx.y * 128;
  const int t = threadIdx.x;
#pragma unroll
  for (int i = 0; i < 32; i++) {
    int e = t + i * 256;       // 0..8191
    int s = e >> 6, d = e & 63;
    tile[s][d] = qkvb[(size_t)(s0 + s) * QKV_N + 4608 + kvh * 64 + d];
  }
  __syncthreads();
#pragma unroll
  for (int i = 0; i < 32; i++) {
    int e = t + i * 256;
    int d = e >> 7, s = e & 127;
    Vt[((size_t)kvh * 64 + d) * 1024 + s0 + s] = tile[s][d];
  }
}

// ---------------- NT bf16 MFMA GEMM: C[M][N] = A[M][K] * B[N][K]^T + bias ----------------
template <bool BF16_OUT>
__global__ __launch_bounds__(256) void gemm_bt(
    const unsigned short* __restrict__ A, const unsigned short* __restrict__ B,
    const float* __restrict__ bias, void* __restrict__ Cv, int M, int N, int K) {
  __shared__ __align__(16) unsigned short As[128 * 32];
  __shared__ __align__(16) unsigned short Bs[128 * 32];
  const int t = threadIdx.x;
  const int l = t & 63;
  const int w = t >> 6;
  const int lr = l & 15, lq = l >> 4;
  const int m0 = blockIdx.y * 128, n0 = blockIdx.x * 128;
  const int wm = (w >> 1) * 64, wn = (w & 1) * 64;

  const int rowA = t >> 2;
  const int kg = (t & 3) * 8;

  int rb0 = n0 + rowA;      if (rb0 > N - 1) rb0 = N - 1;
  int rb1 = n0 + rowA + 64; if (rb1 > N - 1) rb1 = N - 1;

  const unsigned short* gA0 = A + (size_t)(m0 + rowA) * K + kg;
  const unsigned short* gA1 = gA0 + (size_t)64 * K;
  const unsigned short* gB0 = B + (size_t)rb0 * K + kg;
  const unsigned short* gB1 = B + (size_t)rb1 * K + kg;

  unsigned short* lA0 = &As[t * 8];
  unsigned short* lA1 = &As[(t + 256) * 8];
  unsigned short* lB0 = &Bs[t * 8];
  unsigned short* lB1 = &Bs[(t + 256) * 8];

  f32x4 acc[4][4] = {};

  for (int k0 = 0; k0 < K; k0 += 32) {
    async_copy16(gA0 + k0, lA0);
    async_copy16(gA1 + k0, lA1);
    async_copy16(gB0 + k0, lB0);
    async_copy16(gB1 + k0, lB1);
    __syncthreads();
    bf16x8 af[4], bf[4];
#pragma unroll
    for (int i = 0; i < 4; i++)
      af[i] = *(const bf16x8*)&As[(wm + i * 16 + lr) * 32 + lq * 8];
#pragma unroll
    for (int i = 0; i < 4; i++)
      bf[i] = *(const bf16x8*)&Bs[(wn + i * 16 + lr) * 32 + lq * 8];
#pragma unroll
    for (int mi = 0; mi < 4; mi++)
#pragma unroll
      for (int ni = 0; ni < 4; ni++)
        acc[mi][ni] = __builtin_amdgcn_mfma_f32_16x16x32_bf16(af[mi], bf[ni], acc[mi][ni], 0, 0, 0);
    __syncthreads();
  }

#pragma unroll
  for (int mi = 0; mi < 4; mi++) {
#pragma unroll
    for (int ni = 0; ni < 4; ni++) {
      int col = n0 + wn + ni * 16 + lr;
      if (col < N) {
        float bv = bias[col];
#pragma unroll
        for (int r = 0; r < 4; r++) {
          int row = m0 + wm + mi * 16 + lq * 4 + r;
          float val = acc[mi][ni][r] + bv;
          if (BF16_OUT)
            ((unsigned short*)Cv)[(size_t)row * N + col] = f2bf(val);
          else
            ((float*)Cv)[(size_t)row * N + col] = val;
        }
      }
    }
  }
}

// ---------------- MFMA flash attention, sliding window + sinks ----------------
// 1 wave per block = (head, 16-query tile). Sc^T = K·Q^T via MFMA; online softmax
// in C-layout (row=key, col=query -> per-lane state); P^T -> B-layout via LDS;
// O^T = V^T·P^T via MFMA. Window/causal/OOB handled by masking to -3e38 (p==0).
__global__ __launch_bounds__(64) void attn_mfma(
    const unsigned short* __restrict__ Qb,   // [S][H][64] bf16 (pre-scaled)
    const unsigned short* __restrict__ Kb,   // [S][KV][64] bf16
    const unsigned short* __restrict__ Vt,   // [KV*64][S] bf16 (+slack)
    const float* __restrict__ sinks,
    unsigned short* __restrict__ out) {      // [S][4096] bf16
  const int h = blockIdx.x;
  const int q0 = blockIdx.y * 16;
  const int kvh = h >> 3;
  const int l = threadIdx.x;
  const int n = l & 15;   // query col (and A m-index on loads)
  const int g = l >> 4;   // lane group

  __shared__ __align__(16) unsigned short Pl[16][32];

  const unsigned short* qp = Qb + (((size_t)(q0 + n) * 64 + h) * 64 + g * 8);
  bf16x8 qf0 = *(const bf16x8*)qp;
  bf16x8 qf1 = *(const bf16x8*)(qp + 32);

  const int q_lane = q0 + n;
  int k_lo = q0 - 127; if (k_lo < 0) k_lo = 0;
  k_lo &= ~31;                       // 32-align so all frag loads stay 16B-aligned
  const int k_end = q0 + 16;

  float m = -3.0e38f, lsum = 0.0f;
  f32x4 oacc[4] = {};

  for (int kk = k_lo; kk < k_end; kk += 32) {
    // ---- scores for keys kk..kk+31 (two 16-key tiles) ----
    int kr0 = kk + n;      if (kr0 > 1023) kr0 = 1023;
    int kr1 = kk + 16 + n; if (kr1 > 1023) kr1 = 1023;
    const unsigned short* kp0 = Kb + (((size_t)kr0 * 8 + kvh) * 64 + g * 8);
    const unsigned short* kp1 = Kb + (((size_t)kr1 * 8 + kvh) * 64 + g * 8);
    bf16x8 ka0 = *(const bf16x8*)kp0;
    bf16x8 ka1 = *(const bf16x8*)(kp0 + 32);
    bf16x8 kb0 = *(const bf16x8*)kp1;
    bf16x8 kb1 = *(const bf16x8*)(kp1 + 32);
    f32x4 st0 = {}, st1 = {};
    st0 = __builtin_amdgcn_mfma_f32_16x16x32_bf16(ka0, qf0, st0, 0, 0, 0);
    st0 = __builtin_amdgcn_mfma_f32_16x16x32_bf16(ka1, qf1, st0, 0, 0, 0);
    st1 = __builtin_amdgcn_mfma_f32_16x16x32_bf16(kb0, qf0, st1, 0, 0, 0);
    st1 = __builtin_amdgcn_mfma_f32_16x16x32_bf16(kb1, qf1, st1, 0, 0, 0);

    // ---- mask + tile max ----
    float tm = -3.0e38f;
#pragma unroll
    for (int r = 0; r < 4; r++) {
      int k0i = kk + 4 * g + r;
      int k1i = k0i + 16;
      bool ok0 = (k0i <= q_lane) && (q_lane - k0i < 128);
      bool ok1 = (k1i <= q_lane) && (q_lane - k1i < 128);
      st0[r] = ok0 ? st0[r] : -3.0e38f;
      st1[r] = ok1 ? st1[r] : -3.0e38f;
      tm = fmaxf(tm, fmaxf(st0[r], st1[r]));
    }
    tm = fmaxf(tm, __shfl_xor(tm, 16));
    tm = fmaxf(tm, __shfl_xor(tm, 32));

    // ---- online softmax update (per-lane query state, replicated x4 groups) ----
    float mn = fmaxf(m, tm);
    float corr = __expf(m - mn);
    m = mn;
    float p0[4], p1[4], ps = 0.0f;
#pragma unroll
    for (int r = 0; r < 4; r++) {
      p0[r] = __expf(st0[r] - mn);
      p1[r] = __expf(st1[r] - mn);
      ps += p0[r] + p1[r];
    }
    ps += __shfl_xor(ps, 16);
    ps += __shfl_xor(ps, 32);
    lsum = lsum * corr + ps;

    // ---- P^T C-layout -> B-layout via LDS (lane's 8 p's share query row n) ----
    ushort4 w0, w1;
    w0.x = f2bf(p0[0]); w0.y = f2bf(p0[1]); w0.z = f2bf(p0[2]); w0.w = f2bf(p0[3]);
    w1.x = f2bf(p1[0]); w1.y = f2bf(p1[1]); w1.z = f2bf(p1[2]); w1.w = f2bf(p1[3]);
    *(ushort4*)&Pl[n][4 * g]      = w0;
    *(ushort4*)&Pl[n][16 + 4 * g] = w1;
    __syncthreads();
    bf16x8 pf = *(const bf16x8*)&Pl[n][8 * g];
    __syncthreads();  // pf in regs; safe to overwrite next iter

    // ---- O^T += V^T · P^T ----
#pragma unroll
    for (int db = 0; db < 4; db++) {
      const unsigned short* vp = Vt + ((size_t)(kvh * 64 + db * 16 + n)) * 1024 + kk + 8 * g;
      bf16x8 vf = *(const bf16x8*)vp;  // may touch slack past S; p==0 there
#pragma unroll
      for (int r = 0; r < 4; r++) oacc[db][r] *= corr;
      oacc[db] = __builtin_amdgcn_mfma_f32_16x16x32_bf16(vf, pf, oacc[db], 0, 0, 0);
    }
  }

  // ---- sink folded into denominator; finalize ----
  float sink = sinks[h];
  float mn2 = fmaxf(m, sink);
  float corr2 = __expf(m - mn2);
  float denom = lsum * corr2 + __expf(sink - mn2);
  float fs = corr2 / denom;

#pragma unroll
  for (int db = 0; db < 4; db++) {
    ushort4 r;
    r.x = f2bf(oacc[db][0] * fs);
    r.y = f2bf(oacc[db][1] * fs);
    r.z = f2bf(oacc[db][2] * fs);
    r.w = f2bf(oacc[db][3] * fs);
    *(ushort4*)(out + (size_t)q_lane * 4096 + h * 64 + db * 16 + 4 * g) = r;
  }
}

extern "C" void kernel_launch(void* const* d_in, const int* in_sizes, int n_in,
                              void* d_out, int out_size, void* d_ws, size_t ws_size,
                              hipStream_t stream) {
  const float* x = (const float*)d_in[0];
  const int* positions = (const int*)d_in[1];
  const float* Wq = (const float*)d_in[2];
  const float* bq = (const float*)d_in[3];
  const float* Wk = (const float*)d_in[4];
  const float* bk = (const float*)d_in[5];
  const float* Wv = (const float*)d_in[6];
  const float* bv = (const float*)d_in[7];
  const float* Wo = (const float*)d_in[8];
  const float* bo = (const float*)d_in[9];
  const float* sinks = (const float*)d_in[10];
  float* out = (float*)d_out;

  char* ws = (char*)d_ws;
  unsigned short* xb    = (unsigned short*)(ws + 0);           // 1024x2880 bf16
  unsigned short* wqkv  = (unsigned short*)(ws + 5898240);     // 5120x2880 bf16
  unsigned short* wo    = (unsigned short*)(ws + 35389440);    // 2880x4096 bf16
  float* bqkv           = (float*)(ws + 58982400);             // 5120 f32
  unsigned short* qkvb  = (unsigned short*)(ws + 59002880);    // 1024x5120 bf16
  unsigned short* attnb = (unsigned short*)(ws + 69488640);    // 1024x4096 bf16
  unsigned short* Qb    = (unsigned short*)(ws + 77877248);    // 1024x64x64 bf16
  unsigned short* Kb    = (unsigned short*)(ws + 86265856);    // 1024x8x64 bf16
  unsigned short* Vt    = (unsigned short*)(ws + 87314432);    // 8x64x1024 bf16 (+4KB slack)
  float* cosT           = (float*)(ws + 88367104);             // 1024x32 f32
  float* sinT           = (float*)(ws + 88498176);             // 1024x32 f32

  cvt_bf16<<<2880, 256, 0, stream>>>(x, xb, 737280);
  cvt_bf16<<<11520, 256, 0, stream>>>(Wq, wqkv, 2949120);
  cvt_bf16<<<1440, 256, 0, stream>>>(Wk, wqkv + (size_t)4096 * 2880, 368640);
  cvt_bf16<<<1440, 256, 0, stream>>>(Wv, wqkv + (size_t)4608 * 2880, 368640);
  cvt_bf16<<<11520, 256, 0, stream>>>(Wo, wo, 2949120);
  concat_bias<<<20, 256, 0, stream>>>(bq, bk, bv, bqkv);

  const double TWO_PI = 6.283185307179586;
  double lowd = 64.0 * log(4096.0 / (32.0 * TWO_PI)) / (2.0 * log(150000.0));
  if (lowd < 0.0) lowd = 0.0;
  double highd = 64.0 * log(4096.0 / (1.0 * TWO_PI)) / (2.0 * log(150000.0));
  if (highd > 31.0) highd = 31.0;
  if (lowd == highd) highd += 0.001;
  float mscale = (float)(0.1 * log(32.0) + 1.0);
  rope_tables<<<128, 256, 0, stream>>>(positions, cosT, sinT, (float)lowd, (float)highd, mscale);

  // QKV projection -> bf16 [1024][5120]
  gemm_bt<true><<<dim3(40, 8), 256, 0, stream>>>(xb, wqkv, bqkv, qkvb, 1024, 5120, 2880);
  rope_kernel<<<9216, 256, 0, stream>>>(qkvb, cosT, sinT, Qb, Kb);
  v_transpose<<<dim3(8, 8), 256, 0, stream>>>(qkvb, Vt);
  attn_mfma<<<dim3(64, 64), 64, 0, stream>>>(Qb, Kb, Vt, sinks, attnb);
  // Output projection -> fp32 [1024][2880]
  gemm_bt<false><<<dim3(23, 8), 256, 0, stream>>>(attnb, wo, bo, out, 1024, 2880, 4096);
}

// Round 3
// 338.864 us; speedup vs baseline: 1.4403x; 1.1019x over previous
//
#include <hip/hip_runtime.h>
#include <math.h>

#define S_LEN 1024
#define QKV_N 5120

typedef __attribute__((ext_vector_type(8))) __bf16 bf16x8;
typedef __attribute__((ext_vector_type(4))) float f32x4;

__device__ __forceinline__ unsigned short f2bf(float f) {
  unsigned int u = __float_as_uint(f);
  u += 0x7fff + ((u >> 16) & 1);
  return (unsigned short)(u >> 16);
}
__device__ __forceinline__ float bf2f(unsigned short u) {
  return __uint_as_float((unsigned int)u << 16);
}

__device__ __forceinline__ void async_copy16(const void* g, void* l) {
  __builtin_amdgcn_global_load_lds(
      (const __attribute__((address_space(1))) unsigned int*)g,
      (__attribute__((address_space(3))) unsigned int*)l, 16, 0, 0);
}

// ---------------- fp32 -> bf16 convert (vectorized x4) ----------------
__global__ void cvt_bf16(const float* __restrict__ in, unsigned short* __restrict__ out, int n4) {
  int i = blockIdx.x * 256 + threadIdx.x;
  if (i >= n4) return;
  float4 v = ((const float4*)in)[i];
  ushort4 r;
  r.x = f2bf(v.x); r.y = f2bf(v.y); r.z = f2bf(v.z); r.w = f2bf(v.w);
  ((ushort4*)out)[i] = r;
}

__global__ void concat_bias(const float* __restrict__ bq, const float* __restrict__ bk,
                            const float* __restrict__ bv, float* __restrict__ o) {
  int i = blockIdx.x * 256 + threadIdx.x;
  if (i >= 5120) return;
  o[i] = (i < 4096) ? bq[i] : ((i < 4608) ? bk[i - 4096] : bv[i - 4608]);
}

// ---------------- YaRN rope tables: cos/sin [S][32] ----------------
__global__ void rope_tables(const int* __restrict__ positions, float* __restrict__ cosT,
                            float* __restrict__ sinT, float low, float high, float mscale) {
  int idx = blockIdx.x * 256 + threadIdx.x;  // S*32
  if (idx >= S_LEN * 32) return;
  int j = idx & 31, s = idx >> 5;
  float pf = powf(150000.0f, (float)j / 32.0f);
  float ramp = ((float)j - low) / (high - low);
  ramp = fminf(fmaxf(ramp, 0.0f), 1.0f);
  float invf = (1.0f / (32.0f * pf)) * ramp + (1.0f / pf) * (1.0f - ramp);
  float ang = (float)positions[s] * invf;
  cosT[idx] = cosf(ang) * mscale;
  sinT[idx] = sinf(ang) * mscale;
}

// ---------------- rope: qkvb (bf16) -> Qb (scaled bf16), Kb (bf16) ----------------
__global__ void rope_kernel(const unsigned short* __restrict__ qkvb,
                            const float* __restrict__ cosT, const float* __restrict__ sinT,
                            unsigned short* __restrict__ Qb, unsigned short* __restrict__ Kb) {
  int idx = blockIdx.x * 256 + threadIdx.x;  // S*72*32
  if (idx >= S_LEN * 72 * 32) return;
  int j = idx & 31;
  int hh = (idx >> 5) % 72;
  int s = idx / (72 * 32);
  const unsigned short* base = qkvb + (size_t)s * QKV_N + hh * 64;
  float x = bf2f(base[j]), y = bf2f(base[j + 32]);
  float c = cosT[s * 32 + j], sn = sinT[s * 32 + j];
  float o1 = x * c - y * sn;
  float o2 = y * c + x * sn;
  if (hh < 64) {
    unsigned short* q = Qb + ((size_t)s * 64 + hh) * 64;
    q[j]      = f2bf(o1 * 0.125f);   // fold in D^-0.5
    q[j + 32] = f2bf(o2 * 0.125f);
  } else {
    unsigned short* k = Kb + ((size_t)s * 8 + (hh - 64)) * 64;
    k[j]      = f2bf(o1);
    k[j + 32] = f2bf(o2);
  }
}

// ---------------- V transpose: qkvb v-cols -> Vt[KV*64 dims][S] bf16 ----------------
__global__ __launch_bounds__(256) void v_transpose(const unsigned short* __restrict__ qkvb,
                                                   unsigned short* __restrict__ Vt) {
  __shared__ unsigned short tile[128][66];
  const int kvh = blockIdx.x, s0 = blockIdx.y * 128;
  const int t = threadIdx.x;
#pragma unroll
  for (int i = 0; i < 32; i++) {
    int e = t + i * 256;
    int s = e >> 6, d = e & 63;
    tile[s][d] = qkvb[(size_t)(s0 + s) * QKV_N + 4608 + kvh * 64 + d];
  }
  __syncthreads();
#pragma unroll
  for (int i = 0; i < 32; i++) {
    int e = t + i * 256;
    int d = e >> 7, s = e & 127;
    Vt[((size_t)kvh * 64 + d) * 1024 + s0 + s] = tile[s][d];
  }
}

// ---------------- NT bf16 MFMA GEMM, split-K partials ----------------
// grid = (m_tiles, n_tiles, SPLIT); blockIdx.x = m-tile (fastest) so co-launched
// blocks share the same B n-tile (L2 reuse). Partial fp32 sums -> part[s][M][N].
__global__ __launch_bounds__(256) void gemm_bt_sk(
    const unsigned short* __restrict__ A, const unsigned short* __restrict__ B,
    float* __restrict__ part, int M, int N, int K) {
  __shared__ __align__(16) unsigned short As[128 * 32];
  __shared__ __align__(16) unsigned short Bs[128 * 32];
  const int t = threadIdx.x;
  const int l = t & 63;
  const int w = t >> 6;
  const int lr = l & 15, lq = l >> 4;
  const int m0 = blockIdx.x * 128, n0 = blockIdx.y * 128;
  const int s = blockIdx.z, SP = gridDim.z;
  const int wm = (w >> 1) * 64, wn = (w & 1) * 64;

  const int T = K >> 5;                       // 32-wide k-iters
  const int kb = ((s * T) / SP) * 32;
  const int ke = (((s + 1) * T) / SP) * 32;

  const int rowA = t >> 2;
  const int kg = (t & 3) * 8;

  int rb0 = n0 + rowA;      if (rb0 > N - 1) rb0 = N - 1;
  int rb1 = n0 + rowA + 64; if (rb1 > N - 1) rb1 = N - 1;

  const unsigned short* gA0 = A + (size_t)(m0 + rowA) * K + kg;
  const unsigned short* gA1 = gA0 + (size_t)64 * K;
  const unsigned short* gB0 = B + (size_t)rb0 * K + kg;
  const unsigned short* gB1 = B + (size_t)rb1 * K + kg;

  unsigned short* lA0 = &As[t * 8];
  unsigned short* lA1 = &As[(t + 256) * 8];
  unsigned short* lB0 = &Bs[t * 8];
  unsigned short* lB1 = &Bs[(t + 256) * 8];

  f32x4 acc[4][4] = {};

  for (int k0 = kb; k0 < ke; k0 += 32) {
    async_copy16(gA0 + k0, lA0);
    async_copy16(gA1 + k0, lA1);
    async_copy16(gB0 + k0, lB0);
    async_copy16(gB1 + k0, lB1);
    __syncthreads();
    bf16x8 af[4], bf[4];
#pragma unroll
    for (int i = 0; i < 4; i++)
      af[i] = *(const bf16x8*)&As[(wm + i * 16 + lr) * 32 + lq * 8];
#pragma unroll
    for (int i = 0; i < 4; i++)
      bf[i] = *(const bf16x8*)&Bs[(wn + i * 16 + lr) * 32 + lq * 8];
#pragma unroll
    for (int mi = 0; mi < 4; mi++)
#pragma unroll
      for (int ni = 0; ni < 4; ni++)
        acc[mi][ni] = __builtin_amdgcn_mfma_f32_16x16x32_bf16(af[mi], bf[ni], acc[mi][ni], 0, 0, 0);
    __syncthreads();
  }

  float* P = part + (size_t)s * M * N;
#pragma unroll
  for (int mi = 0; mi < 4; mi++) {
#pragma unroll
    for (int ni = 0; ni < 4; ni++) {
      int col = n0 + wn + ni * 16 + lr;
      if (col < N) {
#pragma unroll
        for (int r = 0; r < 4; r++) {
          int row = m0 + wm + mi * 16 + lq * 4 + r;
          P[(size_t)row * N + col] = acc[mi][ni][r];
        }
      }
    }
  }
}

// ---------------- split-K reduce: sum partials + bias -> bf16 ----------------
__global__ void reduce_bf16(const float* __restrict__ part, const float* __restrict__ bias,
                            unsigned short* __restrict__ out, int n4, int ncols4, int SP) {
  int i = blockIdx.x * 256 + threadIdx.x;
  if (i >= n4) return;
  float4 a = ((const float4*)part)[i];
  for (int s = 1; s < SP; s++) {
    float4 b = ((const float4*)part)[(size_t)s * n4 + i];
    a.x += b.x; a.y += b.y; a.z += b.z; a.w += b.w;
  }
  float4 bv = ((const float4*)bias)[i % ncols4];
  ushort4 r;
  r.x = f2bf(a.x + bv.x); r.y = f2bf(a.y + bv.y);
  r.z = f2bf(a.z + bv.z); r.w = f2bf(a.w + bv.w);
  ((ushort4*)out)[i] = r;
}

// ---------------- split-K reduce: sum partials + bias -> fp32 ----------------
__global__ void reduce_f32(const float* __restrict__ part, const float* __restrict__ bias,
                           float* __restrict__ out, int n4, int ncols4, int SP) {
  int i = blockIdx.x * 256 + threadIdx.x;
  if (i >= n4) return;
  float4 a = ((const float4*)part)[i];
  for (int s = 1; s < SP; s++) {
    float4 b = ((const float4*)part)[(size_t)s * n4 + i];
    a.x += b.x; a.y += b.y; a.z += b.z; a.w += b.w;
  }
  float4 bv = ((const float4*)bias)[i % ncols4];
  a.x += bv.x; a.y += bv.y; a.z += bv.z; a.w += bv.w;
  ((float4*)out)[i] = a;
}

// ---------------- MFMA flash attention, sliding window + sinks ----------------
__global__ __launch_bounds__(64) void attn_mfma(
    const unsigned short* __restrict__ Qb,   // [S][H][64] bf16 (pre-scaled)
    const unsigned short* __restrict__ Kb,   // [S][KV][64] bf16
    const unsigned short* __restrict__ Vt,   // [KV*64][S] bf16 (+slack)
    const float* __restrict__ sinks,
    unsigned short* __restrict__ out) {      // [S][4096] bf16
  const int h = blockIdx.x;
  const int q0 = blockIdx.y * 16;
  const int kvh = h >> 3;
  const int l = threadIdx.x;
  const int n = l & 15;
  const int g = l >> 4;

  __shared__ __align__(16) unsigned short Pl[16][32];

  const unsigned short* qp = Qb + (((size_t)(q0 + n) * 64 + h) * 64 + g * 8);
  bf16x8 qf0 = *(const bf16x8*)qp;
  bf16x8 qf1 = *(const bf16x8*)(qp + 32);

  const int q_lane = q0 + n;
  int k_lo = q0 - 127; if (k_lo < 0) k_lo = 0;
  k_lo &= ~31;
  const int k_end = q0 + 16;

  float m = -3.0e38f, lsum = 0.0f;
  f32x4 oacc[4] = {};

  for (int kk = k_lo; kk < k_end; kk += 32) {
    int kr0 = kk + n;      if (kr0 > 1023) kr0 = 1023;
    int kr1 = kk + 16 + n; if (kr1 > 1023) kr1 = 1023;
    const unsigned short* kp0 = Kb + (((size_t)kr0 * 8 + kvh) * 64 + g * 8);
    const unsigned short* kp1 = Kb + (((size_t)kr1 * 8 + kvh) * 64 + g * 8);
    bf16x8 ka0 = *(const bf16x8*)kp0;
    bf16x8 ka1 = *(const bf16x8*)(kp0 + 32);
    bf16x8 kb0 = *(const bf16x8*)kp1;
    bf16x8 kb1 = *(const bf16x8*)(kp1 + 32);
    f32x4 st0 = {}, st1 = {};
    st0 = __builtin_amdgcn_mfma_f32_16x16x32_bf16(ka0, qf0, st0, 0, 0, 0);
    st0 = __builtin_amdgcn_mfma_f32_16x16x32_bf16(ka1, qf1, st0, 0, 0, 0);
    st1 = __builtin_amdgcn_mfma_f32_16x16x32_bf16(kb0, qf0, st1, 0, 0, 0);
    st1 = __builtin_amdgcn_mfma_f32_16x16x32_bf16(kb1, qf1, st1, 0, 0, 0);

    float tm = -3.0e38f;
#pragma unroll
    for (int r = 0; r < 4; r++) {
      int k0i = kk + 4 * g + r;
      int k1i = k0i + 16;
      bool ok0 = (k0i <= q_lane) && (q_lane - k0i < 128);
      bool ok1 = (k1i <= q_lane) && (q_lane - k1i < 128);
      st0[r] = ok0 ? st0[r] : -3.0e38f;
      st1[r] = ok1 ? st1[r] : -3.0e38f;
      tm = fmaxf(tm, fmaxf(st0[r], st1[r]));
    }
    tm = fmaxf(tm, __shfl_xor(tm, 16));
    tm = fmaxf(tm, __shfl_xor(tm, 32));

    float mn = fmaxf(m, tm);
    float corr = __expf(m - mn);
    m = mn;
    float p0[4], p1[4], ps = 0.0f;
#pragma unroll
    for (int r = 0; r < 4; r++) {
      p0[r] = __expf(st0[r] - mn);
      p1[r] = __expf(st1[r] - mn);
      ps += p0[r] + p1[r];
    }
    ps += __shfl_xor(ps, 16);
    ps += __shfl_xor(ps, 32);
    lsum = lsum * corr + ps;

    ushort4 w0, w1;
    w0.x = f2bf(p0[0]); w0.y = f2bf(p0[1]); w0.z = f2bf(p0[2]); w0.w = f2bf(p0[3]);
    w1.x = f2bf(p1[0]); w1.y = f2bf(p1[1]); w1.z = f2bf(p1[2]); w1.w = f2bf(p1[3]);
    *(ushort4*)&Pl[n][4 * g]      = w0;
    *(ushort4*)&Pl[n][16 + 4 * g] = w1;
    __syncthreads();
    bf16x8 pf = *(const bf16x8*)&Pl[n][8 * g];
    __syncthreads();

#pragma unroll
    for (int db = 0; db < 4; db++) {
      const unsigned short* vp = Vt + ((size_t)(kvh * 64 + db * 16 + n)) * 1024 + kk + 8 * g;
      bf16x8 vf = *(const bf16x8*)vp;
#pragma unroll
      for (int r = 0; r < 4; r++) oacc[db][r] *= corr;
      oacc[db] = __builtin_amdgcn_mfma_f32_16x16x32_bf16(vf, pf, oacc[db], 0, 0, 0);
    }
  }

  float sink = sinks[h];
  float mn2 = fmaxf(m, sink);
  float corr2 = __expf(m - mn2);
  float denom = lsum * corr2 + __expf(sink - mn2);
  float fs = corr2 / denom;

#pragma unroll
  for (int db = 0; db < 4; db++) {
    ushort4 r;
    r.x = f2bf(oacc[db][0] * fs);
    r.y = f2bf(oacc[db][1] * fs);
    r.z = f2bf(oacc[db][2] * fs);
    r.w = f2bf(oacc[db][3] * fs);
    *(ushort4*)(out + (size_t)q_lane * 4096 + h * 64 + db * 16 + 4 * g) = r;
  }
}

extern "C" void kernel_launch(void* const* d_in, const int* in_sizes, int n_in,
                              void* d_out, int out_size, void* d_ws, size_t ws_size,
                              hipStream_t stream) {
  const float* x = (const float*)d_in[0];
  const int* positions = (const int*)d_in[1];
  const float* Wq = (const float*)d_in[2];
  const float* bq = (const float*)d_in[3];
  const float* Wk = (const float*)d_in[4];
  const float* bk = (const float*)d_in[5];
  const float* Wv = (const float*)d_in[6];
  const float* bv = (const float*)d_in[7];
  const float* Wo = (const float*)d_in[8];
  const float* bo = (const float*)d_in[9];
  const float* sinks = (const float*)d_in[10];
  float* out = (float*)d_out;

  char* ws = (char*)d_ws;
  unsigned short* xb    = (unsigned short*)(ws + 0);          // 1024x2880 bf16
  unsigned short* wqkv  = (unsigned short*)(ws + 5898240);    // 5120x2880 bf16
  unsigned short* wo    = (unsigned short*)(ws + 35389440);   // 2880x4096 bf16
  float* bqkv           = (float*)(ws + 58982400);            // 5120 f32
  unsigned short* qkvb  = (unsigned short*)(ws + 59002880);   // 1024x5120 bf16
  float* cosT           = (float*)(ws + 69488640);            // 1024x32 f32
  float* sinT           = (float*)(ws + 69619712);            // 1024x32 f32
  const size_t R = 69750784;                                  // reuse region
  // Phase A (QKV gemm): qkv_part = R .. R + split_q*20971520
  float* qkv_part       = (float*)(ws + R);
  // Phase B (post-reduce; qkv_part dead):
  unsigned short* Qb    = (unsigned short*)(ws + R);               // 8,388,608
  unsigned short* Kb    = (unsigned short*)(ws + R + 8388608);     // 1,048,576
  unsigned short* Vt    = (unsigned short*)(ws + R + 9437184);     // 1,048,576 +4K slack
  unsigned short* attnb = (unsigned short*)(ws + R + 10489856);    // 8,388,608
  float* out_part       = (float*)(ws + R + 18878464);             // split_o*11,796,480

  int split_q = 1, split_o = 1;
  if (ws_size >= R + 4ull * 20971520) split_q = 4;
  else if (ws_size >= R + 2ull * 20971520) split_q = 2;
  if (ws_size >= R + 18878464 + 4ull * 11796480) split_o = 4;
  else if (ws_size >= R + 18878464 + 2ull * 11796480) split_o = 2;

  cvt_bf16<<<2880, 256, 0, stream>>>(x, xb, 737280);
  cvt_bf16<<<11520, 256, 0, stream>>>(Wq, wqkv, 2949120);
  cvt_bf16<<<1440, 256, 0, stream>>>(Wk, wqkv + (size_t)4096 * 2880, 368640);
  cvt_bf16<<<1440, 256, 0, stream>>>(Wv, wqkv + (size_t)4608 * 2880, 368640);
  cvt_bf16<<<11520, 256, 0, stream>>>(Wo, wo, 2949120);
  concat_bias<<<20, 256, 0, stream>>>(bq, bk, bv, bqkv);

  const double TWO_PI = 6.283185307179586;
  double lowd = 64.0 * log(4096.0 / (32.0 * TWO_PI)) / (2.0 * log(150000.0));
  if (lowd < 0.0) lowd = 0.0;
  double highd = 64.0 * log(4096.0 / (1.0 * TWO_PI)) / (2.0 * log(150000.0));
  if (highd > 31.0) highd = 31.0;
  if (lowd == highd) highd += 0.001;
  float mscale = (float)(0.1 * log(32.0) + 1.0);
  rope_tables<<<128, 256, 0, stream>>>(positions, cosT, sinT, (float)lowd, (float)highd, mscale);

  // QKV projection: split-K partials then reduce -> bf16 [1024][5120]
  gemm_bt_sk<<<dim3(8, 40, split_q), 256, 0, stream>>>(xb, wqkv, qkv_part, 1024, 5120, 2880);
  reduce_bf16<<<5120, 256, 0, stream>>>(qkv_part, bqkv, qkvb, 1310720, 1280, split_q);

  rope_kernel<<<9216, 256, 0, stream>>>(qkvb, cosT, sinT, Qb, Kb);
  v_transpose<<<dim3(8, 8), 256, 0, stream>>>(qkvb, Vt);
  attn_mfma<<<dim3(64, 64), 64, 0, stream>>>(Qb, Kb, Vt, sinks, attnb);

  // Output projection: split-K partials then reduce -> fp32 [1024][2880]
  gemm_bt_sk<<<dim3(8, 23, split_o), 256, 0, stream>>>(attnb, wo, out_part, 1024, 2880, 4096);
  reduce_f32<<<2880, 256, 0, stream>>>(out_part, bo, out, 737280, 720, split_o);
}

// Round 4
// 335.137 us; speedup vs baseline: 1.4564x; 1.0111x over previous
//
#include <hip/hip_runtime.h>
#include <math.h>

#define S_LEN 1024
#define QKV_N 5120

typedef __attribute__((ext_vector_type(8))) __bf16 bf16x8;
typedef __attribute__((ext_vector_type(4))) float f32x4;

__device__ __forceinline__ unsigned short f2bf(float f) {
  unsigned int u = __float_as_uint(f);
  u += 0x7fff + ((u >> 16) & 1);
  return (unsigned short)(u >> 16);
}
__device__ __forceinline__ float bf2f(unsigned short u) {
  return __uint_as_float((unsigned int)u << 16);
}

__device__ __forceinline__ void async_copy16(const void* g, void* l) {
  __builtin_amdgcn_global_load_lds(
      (const __attribute__((address_space(1))) unsigned int*)g,
      (__attribute__((address_space(3))) unsigned int*)l, 16, 0, 0);
}

// ---------------- fp32 -> bf16 convert (vectorized x4) ----------------
__global__ void cvt_bf16(const float* __restrict__ in, unsigned short* __restrict__ out, int n4) {
  int i = blockIdx.x * 256 + threadIdx.x;
  if (i >= n4) return;
  float4 v = ((const float4*)in)[i];
  ushort4 r;
  r.x = f2bf(v.x); r.y = f2bf(v.y); r.z = f2bf(v.z); r.w = f2bf(v.w);
  ((ushort4*)out)[i] = r;
}

__global__ void concat_bias(const float* __restrict__ bq, const float* __restrict__ bk,
                            const float* __restrict__ bv, float* __restrict__ o) {
  int i = blockIdx.x * 256 + threadIdx.x;
  if (i >= 5120) return;
  o[i] = (i < 4096) ? bq[i] : ((i < 4608) ? bk[i - 4096] : bv[i - 4608]);
}

// ---------------- YaRN rope tables: cos/sin [S][32] ----------------
__global__ void rope_tables(const int* __restrict__ positions, float* __restrict__ cosT,
                            float* __restrict__ sinT, float low, float high, float mscale) {
  int idx = blockIdx.x * 256 + threadIdx.x;  // S*32
  if (idx >= S_LEN * 32) return;
  int j = idx & 31, s = idx >> 5;
  float pf = powf(150000.0f, (float)j / 32.0f);
  float ramp = ((float)j - low) / (high - low);
  ramp = fminf(fmaxf(ramp, 0.0f), 1.0f);
  float invf = (1.0f / (32.0f * pf)) * ramp + (1.0f / pf) * (1.0f - ramp);
  float ang = (float)positions[s] * invf;
  cosT[idx] = cosf(ang) * mscale;
  sinT[idx] = sinf(ang) * mscale;
}

// ---------------- fused reduce + rope: bf16 partials -> Qb (scaled), Kb ----------------
__global__ void rope_qk(const unsigned short* __restrict__ part, const float* __restrict__ bqkv,
                        const float* __restrict__ cosT, const float* __restrict__ sinT,
                        unsigned short* __restrict__ Qb, unsigned short* __restrict__ Kb, int SP) {
  int idx = blockIdx.x * 256 + threadIdx.x;  // S*72*32
  if (idx >= S_LEN * 72 * 32) return;
  int j = idx & 31;
  int hh = (idx >> 5) % 72;
  int s = idx / (72 * 32);
  int c1 = hh * 64 + j, c2 = c1 + 32;
  float x = bqkv[c1], y = bqkv[c2];
  for (int sp = 0; sp < SP; sp++) {
    const unsigned short* P = part + (size_t)sp * S_LEN * QKV_N + (size_t)s * QKV_N;
    x += bf2f(P[c1]);
    y += bf2f(P[c2]);
  }
  float c = cosT[s * 32 + j], sn = sinT[s * 32 + j];
  float o1 = x * c - y * sn;
  float o2 = y * c + x * sn;
  if (hh < 64) {
    unsigned short* q = Qb + ((size_t)s * 64 + hh) * 64;
    q[j]      = f2bf(o1 * 0.125f);   // fold in D^-0.5
    q[j + 32] = f2bf(o2 * 0.125f);
  } else {
    unsigned short* k = Kb + ((size_t)s * 8 + (hh - 64)) * 64;
    k[j]      = f2bf(o1);
    k[j + 32] = f2bf(o2);
  }
}

// ---------------- fused reduce + V transpose: partials -> Vt[KV*64][S] ----------------
__global__ __launch_bounds__(256) void v_trans(const unsigned short* __restrict__ part,
                                               const float* __restrict__ bqkv,
                                               unsigned short* __restrict__ Vt, int SP) {
  __shared__ unsigned short tile[128][66];
  const int kvh = blockIdx.x, s0 = blockIdx.y * 128;
  const int t = threadIdx.x;
#pragma unroll
  for (int i = 0; i < 32; i++) {
    int e = t + i * 256;
    int s = e >> 6, d = e & 63;
    int col = 4608 + kvh * 64 + d;
    float v = bqkv[col];
    for (int sp = 0; sp < SP; sp++)
      v += bf2f(part[(size_t)sp * S_LEN * QKV_N + (size_t)(s0 + s) * QKV_N + col]);
    tile[s][d] = f2bf(v);
  }
  __syncthreads();
#pragma unroll
  for (int i = 0; i < 32; i++) {
    int e = t + i * 256;
    int d = e >> 7, s = e & 127;
    Vt[((size_t)kvh * 64 + d) * 1024 + s0 + s] = tile[s][d];
  }
}

// ---------------- NT bf16 MFMA GEMM, split-K, XCD-swizzled 1-D grid ----------------
// combo c = s*NT + n; block lb = (c>>3)*64 + m*8 + (c&7). All 8 m-blocks of a
// combo share lb%8 (= same XCD under round-robin) -> B-tile fetched once, A-slice
// L2-resident per XCD. bf16 partials -> part[s][M][N].
__global__ __launch_bounds__(256) void gemm_bt_sk(
    const unsigned short* __restrict__ A, const unsigned short* __restrict__ B,
    unsigned short* __restrict__ part, int M, int N, int K, int NT, int SP) {
  __shared__ __align__(16) unsigned short As[128 * 32];
  __shared__ __align__(16) unsigned short Bs[128 * 32];
  const int lb = blockIdx.x;
  const int aI = lb >> 6;
  const int rem = lb & 63;
  const int mI = rem >> 3;
  const int bI = rem & 7;
  const int c = aI * 8 + bI;
  if (c >= NT * SP) return;
  const int sI = c / NT, nI = c % NT;
  const int m0 = mI * 128, n0 = nI * 128;

  const int t = threadIdx.x;
  const int l = t & 63;
  const int w = t >> 6;
  const int lr = l & 15, lq = l >> 4;
  const int wm = (w >> 1) * 64, wn = (w & 1) * 64;

  const int T = K >> 5;
  const int kb = ((sI * T) / SP) * 32;
  const int ke = (((sI + 1) * T) / SP) * 32;

  const int rowA = t >> 2;
  const int kg = (t & 3) * 8;

  int rb0 = n0 + rowA;      if (rb0 > N - 1) rb0 = N - 1;
  int rb1 = n0 + rowA + 64; if (rb1 > N - 1) rb1 = N - 1;

  const unsigned short* gA0 = A + (size_t)(m0 + rowA) * K + kg;
  const unsigned short* gA1 = gA0 + (size_t)64 * K;
  const unsigned short* gB0 = B + (size_t)rb0 * K + kg;
  const unsigned short* gB1 = B + (size_t)rb1 * K + kg;

  unsigned short* lA0 = &As[t * 8];
  unsigned short* lA1 = &As[(t + 256) * 8];
  unsigned short* lB0 = &Bs[t * 8];
  unsigned short* lB1 = &Bs[(t + 256) * 8];

  f32x4 acc[4][4] = {};

  for (int k0 = kb; k0 < ke; k0 += 32) {
    async_copy16(gA0 + k0, lA0);
    async_copy16(gA1 + k0, lA1);
    async_copy16(gB0 + k0, lB0);
    async_copy16(gB1 + k0, lB1);
    __syncthreads();
    bf16x8 af[4], bf[4];
#pragma unroll
    for (int i = 0; i < 4; i++)
      af[i] = *(const bf16x8*)&As[(wm + i * 16 + lr) * 32 + lq * 8];
#pragma unroll
    for (int i = 0; i < 4; i++)
      bf[i] = *(const bf16x8*)&Bs[(wn + i * 16 + lr) * 32 + lq * 8];
#pragma unroll
    for (int mi = 0; mi < 4; mi++)
#pragma unroll
      for (int ni = 0; ni < 4; ni++)
        acc[mi][ni] = __builtin_amdgcn_mfma_f32_16x16x32_bf16(af[mi], bf[ni], acc[mi][ni], 0, 0, 0);
    __syncthreads();
  }

  unsigned short* P = part + (size_t)sI * M * N;
#pragma unroll
  for (int mi = 0; mi < 4; mi++) {
#pragma unroll
    for (int ni = 0; ni < 4; ni++) {
      int col = n0 + wn + ni * 16 + lr;
      if (col < N) {
#pragma unroll
        for (int r = 0; r < 4; r++) {
          int row = m0 + wm + mi * 16 + lq * 4 + r;
          P[(size_t)row * N + col] = f2bf(acc[mi][ni][r]);
        }
      }
    }
  }
}

// ---------------- split-K reduce: sum bf16 partials + bias -> fp32 out ----------------
// 8 elements per thread; N=2880 divisible by 8.
__global__ void reduce_f32(const unsigned short* __restrict__ part, const float* __restrict__ bias,
                           float* __restrict__ out, int SP) {
  int i = blockIdx.x * 256 + threadIdx.x;  // 0..368639 (8-elem chunks of 1024x2880)
  if (i >= 368640) return;
  float acc[8];
  int bc = (i % 360) * 8;
#pragma unroll
  for (int e = 0; e < 8; e++) acc[e] = bias[bc + e];
  for (int sp = 0; sp < SP; sp++) {
    const ushort4* P = (const ushort4*)(part + (size_t)sp * 2949120);
    ushort4 u0 = P[i * 2], u1 = P[i * 2 + 1];
    acc[0] += bf2f(u0.x); acc[1] += bf2f(u0.y); acc[2] += bf2f(u0.z); acc[3] += bf2f(u0.w);
    acc[4] += bf2f(u1.x); acc[5] += bf2f(u1.y); acc[6] += bf2f(u1.z); acc[7] += bf2f(u1.w);
  }
  float4 o0 = {acc[0], acc[1], acc[2], acc[3]};
  float4 o1 = {acc[4], acc[5], acc[6], acc[7]};
  ((float4*)out)[i * 2] = o0;
  ((float4*)out)[i * 2 + 1] = o1;
}

// ---------------- MFMA flash attention, sliding window + sinks ----------------
__global__ __launch_bounds__(64) void attn_mfma(
    const unsigned short* __restrict__ Qb,   // [S][H][64] bf16 (pre-scaled)
    const unsigned short* __restrict__ Kb,   // [S][KV][64] bf16
    const unsigned short* __restrict__ Vt,   // [KV*64][S] bf16 (+slack)
    const float* __restrict__ sinks,
    unsigned short* __restrict__ out) {      // [S][4096] bf16
  const int h = blockIdx.x;
  const int q0 = blockIdx.y * 16;
  const int kvh = h >> 3;
  const int l = threadIdx.x;
  const int n = l & 15;
  const int g = l >> 4;

  __shared__ __align__(16) unsigned short Pl[16][32];

  const unsigned short* qp = Qb + (((size_t)(q0 + n) * 64 + h) * 64 + g * 8);
  bf16x8 qf0 = *(const bf16x8*)qp;
  bf16x8 qf1 = *(const bf16x8*)(qp + 32);

  const int q_lane = q0 + n;
  int k_lo = q0 - 127; if (k_lo < 0) k_lo = 0;
  k_lo &= ~31;
  const int k_end = q0 + 16;

  float m = -3.0e38f, lsum = 0.0f;
  f32x4 oacc[4] = {};

  for (int kk = k_lo; kk < k_end; kk += 32) {
    int kr0 = kk + n;      if (kr0 > 1023) kr0 = 1023;
    int kr1 = kk + 16 + n; if (kr1 > 1023) kr1 = 1023;
    const unsigned short* kp0 = Kb + (((size_t)kr0 * 8 + kvh) * 64 + g * 8);
    const unsigned short* kp1 = Kb + (((size_t)kr1 * 8 + kvh) * 64 + g * 8);
    bf16x8 ka0 = *(const bf16x8*)kp0;
    bf16x8 ka1 = *(const bf16x8*)(kp0 + 32);
    bf16x8 kb0 = *(const bf16x8*)kp1;
    bf16x8 kb1 = *(const bf16x8*)(kp1 + 32);
    f32x4 st0 = {}, st1 = {};
    st0 = __builtin_amdgcn_mfma_f32_16x16x32_bf16(ka0, qf0, st0, 0, 0, 0);
    st0 = __builtin_amdgcn_mfma_f32_16x16x32_bf16(ka1, qf1, st0, 0, 0, 0);
    st1 = __builtin_amdgcn_mfma_f32_16x16x32_bf16(kb0, qf0, st1, 0, 0, 0);
    st1 = __builtin_amdgcn_mfma_f32_16x16x32_bf16(kb1, qf1, st1, 0, 0, 0);

    float tm = -3.0e38f;
#pragma unroll
    for (int r = 0; r < 4; r++) {
      int k0i = kk + 4 * g + r;
      int k1i = k0i + 16;
      bool ok0 = (k0i <= q_lane) && (q_lane - k0i < 128);
      bool ok1 = (k1i <= q_lane) && (q_lane - k1i < 128);
      st0[r] = ok0 ? st0[r] : -3.0e38f;
      st1[r] = ok1 ? st1[r] : -3.0e38f;
      tm = fmaxf(tm, fmaxf(st0[r], st1[r]));
    }
    tm = fmaxf(tm, __shfl_xor(tm, 16));
    tm = fmaxf(tm, __shfl_xor(tm, 32));

    float mn = fmaxf(m, tm);
    float corr = __expf(m - mn);
    m = mn;
    float p0[4], p1[4], ps = 0.0f;
#pragma unroll
    for (int r = 0; r < 4; r++) {
      p0[r] = __expf(st0[r] - mn);
      p1[r] = __expf(st1[r] - mn);
      ps += p0[r] + p1[r];
    }
    ps += __shfl_xor(ps, 16);
    ps += __shfl_xor(ps, 32);
    lsum = lsum * corr + ps;

    ushort4 w0, w1;
    w0.x = f2bf(p0[0]); w0.y = f2bf(p0[1]); w0.z = f2bf(p0[2]); w0.w = f2bf(p0[3]);
    w1.x = f2bf(p1[0]); w1.y = f2bf(p1[1]); w1.z = f2bf(p1[2]); w1.w = f2bf(p1[3]);
    *(ushort4*)&Pl[n][4 * g]      = w0;
    *(ushort4*)&Pl[n][16 + 4 * g] = w1;
    __syncthreads();
    bf16x8 pf = *(const bf16x8*)&Pl[n][8 * g];
    __syncthreads();

#pragma unroll
    for (int db = 0; db < 4; db++) {
      const unsigned short* vp = Vt + ((size_t)(kvh * 64 + db * 16 + n)) * 1024 + kk + 8 * g;
      bf16x8 vf = *(const bf16x8*)vp;
#pragma unroll
      for (int r = 0; r < 4; r++) oacc[db][r] *= corr;
      oacc[db] = __builtin_amdgcn_mfma_f32_16x16x32_bf16(vf, pf, oacc[db], 0, 0, 0);
    }
  }

  float sink = sinks[h];
  float mn2 = fmaxf(m, sink);
  float corr2 = __expf(m - mn2);
  float denom = lsum * corr2 + __expf(sink - mn2);
  float fs = corr2 / denom;

#pragma unroll
  for (int db = 0; db < 4; db++) {
    ushort4 r;
    r.x = f2bf(oacc[db][0] * fs);
    r.y = f2bf(oacc[db][1] * fs);
    r.z = f2bf(oacc[db][2] * fs);
    r.w = f2bf(oacc[db][3] * fs);
    *(ushort4*)(out + (size_t)q_lane * 4096 + h * 64 + db * 16 + 4 * g) = r;
  }
}

extern "C" void kernel_launch(void* const* d_in, const int* in_sizes, int n_in,
                              void* d_out, int out_size, void* d_ws, size_t ws_size,
                              hipStream_t stream) {
  const float* x = (const float*)d_in[0];
  const int* positions = (const int*)d_in[1];
  const float* Wq = (const float*)d_in[2];
  const float* bq = (const float*)d_in[3];
  const float* Wk = (const float*)d_in[4];
  const float* bk = (const float*)d_in[5];
  const float* Wv = (const float*)d_in[6];
  const float* bv = (const float*)d_in[7];
  const float* Wo = (const float*)d_in[8];
  const float* bo = (const float*)d_in[9];
  const float* sinks = (const float*)d_in[10];
  float* out = (float*)d_out;

  char* ws = (char*)d_ws;
  unsigned short* xb   = (unsigned short*)(ws + 0);          // 1024x2880 bf16
  unsigned short* wqkv = (unsigned short*)(ws + 5898240);    // 5120x2880 bf16
  unsigned short* wo   = (unsigned short*)(ws + 35389440);   // 2880x4096 bf16
  float* bqkv          = (float*)(ws + 58982400);            // 5120 f32
  float* cosT          = (float*)(ws + 59002880);            // 1024x32 f32
  float* sinT          = (float*)(ws + 59133952);            // 1024x32 f32
  const size_t SH = 59265024;                                // shared region
  // Phase A: qkv_part (bf16, split_q x 10,485,760 bytes) lives at SH
  unsigned short* qkv_part = (unsigned short*)(ws + SH);
  // Phase B (qkv_part dead after rope_qk/v_trans):
  unsigned short* out_part = (unsigned short*)(ws + SH);            // split_o x 5,898,240
  unsigned short* attnb    = (unsigned short*)(ws + SH + 23592960); // 8,388,608
  // Tail (never overlapped):
  const size_t TL = SH + 41943040;
  unsigned short* Qb = (unsigned short*)(ws + TL);                  // 8,388,608
  unsigned short* Kb = (unsigned short*)(ws + TL + 8388608);        // 1,048,576
  unsigned short* Vt = (unsigned short*)(ws + TL + 9437184);        // 1,048,576 + 128 slack

  int split_q = 4, split_o = 4;
  if (ws_size < TL + 10485888) {  // ~111.7 MB full plan
    split_q = 2; split_o = 2;     // fits in ~90.7 MB (regions shrink accordingly)
    attnb = (unsigned short*)(ws + SH + 11796480);
    Qb = (unsigned short*)(ws + SH + 20971520);
    Kb = Qb + 4194304;
    Vt = Kb + 524288;
  }

  cvt_bf16<<<2880, 256, 0, stream>>>(x, xb, 737280);
  cvt_bf16<<<11520, 256, 0, stream>>>(Wq, wqkv, 2949120);
  cvt_bf16<<<1440, 256, 0, stream>>>(Wk, wqkv + (size_t)4096 * 2880, 368640);
  cvt_bf16<<<1440, 256, 0, stream>>>(Wv, wqkv + (size_t)4608 * 2880, 368640);
  cvt_bf16<<<11520, 256, 0, stream>>>(Wo, wo, 2949120);
  concat_bias<<<20, 256, 0, stream>>>(bq, bk, bv, bqkv);

  const double TWO_PI = 6.283185307179586;
  double lowd = 64.0 * log(4096.0 / (32.0 * TWO_PI)) / (2.0 * log(150000.0));
  if (lowd < 0.0) lowd = 0.0;
  double highd = 64.0 * log(4096.0 / (1.0 * TWO_PI)) / (2.0 * log(150000.0));
  if (highd > 31.0) highd = 31.0;
  if (lowd == highd) highd += 0.001;
  float mscale = (float)(0.1 * log(32.0) + 1.0);
  rope_tables<<<128, 256, 0, stream>>>(positions, cosT, sinT, (float)lowd, (float)highd, mscale);

  // QKV projection: split-K bf16 partials (XCD-swizzled grid)
  {
    int NT = 40, C = NT * split_q;
    int grid = 64 * ((C + 7) / 8);
    gemm_bt_sk<<<grid, 256, 0, stream>>>(xb, wqkv, qkv_part, 1024, 5120, 2880, NT, split_q);
  }
  // Fused reduce+rope / reduce+transpose (qkvb eliminated)
  rope_qk<<<9216, 256, 0, stream>>>(qkv_part, bqkv, cosT, sinT, Qb, Kb, split_q);
  v_trans<<<dim3(8, 8), 256, 0, stream>>>(qkv_part, bqkv, Vt, split_q);

  attn_mfma<<<dim3(64, 64), 64, 0, stream>>>(Qb, Kb, Vt, sinks, attnb);

  // Output projection: split-K bf16 partials, then reduce -> fp32
  {
    int NT = 23, C = NT * split_o;
    int grid = 64 * ((C + 7) / 8);
    gemm_bt_sk<<<grid, 256, 0, stream>>>(attnb, wo, out_part, 1024, 2880, 4096, NT, split_o);
  }
  reduce_f32<<<1440, 256, 0, stream>>>(out_part, bo, out, split_o);
}

// Round 5
// 318.038 us; speedup vs baseline: 1.5347x; 1.0538x over previous
//
#include <hip/hip_runtime.h>
#include <math.h>

#define S_LEN 1024
#define QKV_N 5120

typedef __attribute__((ext_vector_type(8))) __bf16 bf16x8;
typedef __attribute__((ext_vector_type(4))) float f32x4;

__device__ __forceinline__ unsigned short f2bf(float f) {
  unsigned int u = __float_as_uint(f);
  u += 0x7fff + ((u >> 16) & 1);
  return (unsigned short)(u >> 16);
}
__device__ __forceinline__ float bf2f(unsigned short u) {
  return __uint_as_float((unsigned int)u << 16);
}

__device__ __forceinline__ void async_copy16(const void* g, void* l) {
  __builtin_amdgcn_global_load_lds(
      (const __attribute__((address_space(1))) unsigned int*)g,
      (__attribute__((address_space(3))) unsigned int*)l, 16, 0, 0);
}

// ---------------- mega-fused prep: all cvt + bias concat + YaRN tables ----------------
// Flat f4-index ladder:
//   [0, 737280)            x -> xb
//   [737280, 3686400)      Wq -> wqkv
//   [3686400, 4055040)     Wk -> wqkv+4096*2880
//   [4055040, 4423680)     Wv -> wqkv+4608*2880
//   [4423680, 7372800)     Wo -> wo
//   [7372800, 7374080)     bias concat (f4 of bqkv)
//   [7374080, 7382272)     rope tables (8192 items: s=tid>>3, j=(tid&7)*4 ..+3)
__global__ void prep_all(const float* __restrict__ x, const float* __restrict__ Wq,
                         const float* __restrict__ Wk, const float* __restrict__ Wv,
                         const float* __restrict__ Wo, const float* __restrict__ bq,
                         const float* __restrict__ bk, const float* __restrict__ bv,
                         const int* __restrict__ positions,
                         unsigned short* __restrict__ xb, unsigned short* __restrict__ wqkv,
                         unsigned short* __restrict__ wo, float* __restrict__ bqkv,
                         float* __restrict__ cosT, float* __restrict__ sinT,
                         float low, float high, float mscale) {
  int i = blockIdx.x * 256 + threadIdx.x;
  if (i < 7372800) {
    const float* src;
    unsigned short* dst;
    int off;
    if (i < 737280)       { src = x;  dst = xb;                          off = i; }
    else if (i < 3686400) { src = Wq; dst = wqkv;                        off = i - 737280; }
    else if (i < 4055040) { src = Wk; dst = wqkv + (size_t)4096 * 2880;  off = i - 3686400; }
    else if (i < 4423680) { src = Wv; dst = wqkv + (size_t)4608 * 2880;  off = i - 4055040; }
    else                  { src = Wo; dst = wo;                          off = i - 4423680; }
    float4 v = ((const float4*)src)[off];
    ushort4 r;
    r.x = f2bf(v.x); r.y = f2bf(v.y); r.z = f2bf(v.z); r.w = f2bf(v.w);
    ((ushort4*)dst)[off] = r;
  } else if (i < 7374080) {
    int b = i - 7372800;           // f4 index into bqkv, c0 = b*4
    int c0 = b * 4;
    float4 v;
    if (c0 < 4096)      v = ((const float4*)bq)[b];
    else if (c0 < 4608) v = ((const float4*)bk)[b - 1024];
    else                v = ((const float4*)bv)[b - 1152];
    ((float4*)bqkv)[b] = v;
  } else if (i < 7382272) {
    int tid = i - 7374080;         // 0..8191
    int s = tid >> 3;
    int j0 = (tid & 7) * 4;
    float pos = (float)positions[s];
    float4 cv, sv;
    float* cc = (float*)&cv;
    float* ss = (float*)&sv;
#pragma unroll
    for (int e = 0; e < 4; e++) {
      int j = j0 + e;
      float pf = powf(150000.0f, (float)j / 32.0f);
      float ramp = ((float)j - low) / (high - low);
      ramp = fminf(fmaxf(ramp, 0.0f), 1.0f);
      float invf = (1.0f / (32.0f * pf)) * ramp + (1.0f / pf) * (1.0f - ramp);
      float ang = pos * invf;
      cc[e] = cosf(ang) * mscale;
      ss[e] = sinf(ang) * mscale;
    }
    ((float4*)cosT)[s * 8 + (tid & 7)] = cv;
    ((float4*)sinT)[s * 8 + (tid & 7)] = sv;
  }
}

// ---------------- fused: (reduce+rope Q,K) | (reduce+transpose V) ----------------
// blocks [0,9216): rope on q/k heads; blocks [9216,9280): V transpose.
__global__ __launch_bounds__(256) void rope_vtrans(
    const unsigned short* __restrict__ part, const float* __restrict__ bqkv,
    const float* __restrict__ cosT, const float* __restrict__ sinT,
    unsigned short* __restrict__ Qb, unsigned short* __restrict__ Kb,
    unsigned short* __restrict__ Vt, int SP) {
  const int bx = blockIdx.x;
  const int t = threadIdx.x;
  __shared__ unsigned short tile[128][66];
  if (bx < 9216) {
    int idx = bx * 256 + t;  // S*72*32
    int j = idx & 31;
    int hh = (idx >> 5) % 72;
    int s = idx / (72 * 32);
    int c1 = hh * 64 + j, c2 = c1 + 32;
    float xv = bqkv[c1], yv = bqkv[c2];
    for (int sp = 0; sp < SP; sp++) {
      const unsigned short* P = part + (size_t)sp * S_LEN * QKV_N + (size_t)s * QKV_N;
      xv += bf2f(P[c1]);
      yv += bf2f(P[c2]);
    }
    float c = cosT[s * 32 + j], sn = sinT[s * 32 + j];
    float o1 = xv * c - yv * sn;
    float o2 = yv * c + xv * sn;
    if (hh < 64) {
      unsigned short* q = Qb + ((size_t)s * 64 + hh) * 64;
      q[j]      = f2bf(o1 * 0.125f);   // fold in D^-0.5
      q[j + 32] = f2bf(o2 * 0.125f);
    } else {
      unsigned short* k = Kb + ((size_t)s * 8 + (hh - 64)) * 64;
      k[j]      = f2bf(o1);
      k[j + 32] = f2bf(o2);
    }
  } else {
    const int b = bx - 9216;
    const int kvh = b >> 3, s0 = (b & 7) * 128;
#pragma unroll
    for (int i = 0; i < 32; i++) {
      int e = t + i * 256;
      int s = e >> 6, d = e & 63;
      int col = 4608 + kvh * 64 + d;
      float v = bqkv[col];
      for (int sp = 0; sp < SP; sp++)
        v += bf2f(part[(size_t)sp * S_LEN * QKV_N + (size_t)(s0 + s) * QKV_N + col]);
      tile[s][d] = f2bf(v);
    }
    __syncthreads();
#pragma unroll
    for (int i = 0; i < 32; i++) {
      int e = t + i * 256;
      int d = e >> 7, s = e & 127;
      Vt[((size_t)kvh * 64 + d) * 1024 + s0 + s] = tile[s][d];
    }
  }
}

// ---------------- NT bf16 MFMA GEMM, split-K, XCD-swizzled 1-D grid ----------------
__global__ __launch_bounds__(256) void gemm_bt_sk(
    const unsigned short* __restrict__ A, const unsigned short* __restrict__ B,
    unsigned short* __restrict__ part, int M, int N, int K, int NT, int SP) {
  __shared__ __align__(16) unsigned short As[128 * 32];
  __shared__ __align__(16) unsigned short Bs[128 * 32];
  const int lb = blockIdx.x;
  const int aI = lb >> 6;
  const int rem = lb & 63;
  const int mI = rem >> 3;
  const int bI = rem & 7;
  const int c = aI * 8 + bI;
  if (c >= NT * SP) return;
  const int sI = c / NT, nI = c % NT;
  const int m0 = mI * 128, n0 = nI * 128;

  const int t = threadIdx.x;
  const int l = t & 63;
  const int w = t >> 6;
  const int lr = l & 15, lq = l >> 4;
  const int wm = (w >> 1) * 64, wn = (w & 1) * 64;

  const int T = K >> 5;
  const int kb = ((sI * T) / SP) * 32;
  const int ke = (((sI + 1) * T) / SP) * 32;

  const int rowA = t >> 2;
  const int kg = (t & 3) * 8;

  int rb0 = n0 + rowA;      if (rb0 > N - 1) rb0 = N - 1;
  int rb1 = n0 + rowA + 64; if (rb1 > N - 1) rb1 = N - 1;

  const unsigned short* gA0 = A + (size_t)(m0 + rowA) * K + kg;
  const unsigned short* gA1 = gA0 + (size_t)64 * K;
  const unsigned short* gB0 = B + (size_t)rb0 * K + kg;
  const unsigned short* gB1 = B + (size_t)rb1 * K + kg;

  unsigned short* lA0 = &As[t * 8];
  unsigned short* lA1 = &As[(t + 256) * 8];
  unsigned short* lB0 = &Bs[t * 8];
  unsigned short* lB1 = &Bs[(t + 256) * 8];

  f32x4 acc[4][4] = {};

  for (int k0 = kb; k0 < ke; k0 += 32) {
    async_copy16(gA0 + k0, lA0);
    async_copy16(gA1 + k0, lA1);
    async_copy16(gB0 + k0, lB0);
    async_copy16(gB1 + k0, lB1);
    __syncthreads();
    bf16x8 af[4], bf[4];
#pragma unroll
    for (int i = 0; i < 4; i++)
      af[i] = *(const bf16x8*)&As[(wm + i * 16 + lr) * 32 + lq * 8];
#pragma unroll
    for (int i = 0; i < 4; i++)
      bf[i] = *(const bf16x8*)&Bs[(wn + i * 16 + lr) * 32 + lq * 8];
#pragma unroll
    for (int mi = 0; mi < 4; mi++)
#pragma unroll
      for (int ni = 0; ni < 4; ni++)
        acc[mi][ni] = __builtin_amdgcn_mfma_f32_16x16x32_bf16(af[mi], bf[ni], acc[mi][ni], 0, 0, 0);
    __syncthreads();
  }

  unsigned short* P = part + (size_t)sI * M * N;
#pragma unroll
  for (int mi = 0; mi < 4; mi++) {
#pragma unroll
    for (int ni = 0; ni < 4; ni++) {
      int col = n0 + wn + ni * 16 + lr;
      if (col < N) {
#pragma unroll
        for (int r = 0; r < 4; r++) {
          int row = m0 + wm + mi * 16 + lq * 4 + r;
          P[(size_t)row * N + col] = f2bf(acc[mi][ni][r]);
        }
      }
    }
  }
}

// ---------------- split-K reduce: sum bf16 partials + bias -> fp32 out ----------------
__global__ void reduce_f32(const unsigned short* __restrict__ part, const float* __restrict__ bias,
                           float* __restrict__ out, int SP) {
  int i = blockIdx.x * 256 + threadIdx.x;  // 0..368639 (8-elem chunks of 1024x2880)
  if (i >= 368640) return;
  float acc[8];
  int bc = (i % 360) * 8;
#pragma unroll
  for (int e = 0; e < 8; e++) acc[e] = bias[bc + e];
  for (int sp = 0; sp < SP; sp++) {
    const ushort4* P = (const ushort4*)(part + (size_t)sp * 2949120);
    ushort4 u0 = P[i * 2], u1 = P[i * 2 + 1];
    acc[0] += bf2f(u0.x); acc[1] += bf2f(u0.y); acc[2] += bf2f(u0.z); acc[3] += bf2f(u0.w);
    acc[4] += bf2f(u1.x); acc[5] += bf2f(u1.y); acc[6] += bf2f(u1.z); acc[7] += bf2f(u1.w);
  }
  float4 o0 = {acc[0], acc[1], acc[2], acc[3]};
  float4 o1 = {acc[4], acc[5], acc[6], acc[7]};
  ((float4*)out)[i * 2] = o0;
  ((float4*)out)[i * 2 + 1] = o1;
}

// ---------------- MFMA flash attention, sliding window + sinks ----------------
__global__ __launch_bounds__(64) void attn_mfma(
    const unsigned short* __restrict__ Qb,   // [S][H][64] bf16 (pre-scaled)
    const unsigned short* __restrict__ Kb,   // [S][KV][64] bf16
    const unsigned short* __restrict__ Vt,   // [KV*64][S] bf16 (+slack)
    const float* __restrict__ sinks,
    unsigned short* __restrict__ out) {      // [S][4096] bf16
  const int h = blockIdx.x;
  const int q0 = blockIdx.y * 16;
  const int kvh = h >> 3;
  const int l = threadIdx.x;
  const int n = l & 15;
  const int g = l >> 4;

  __shared__ __align__(16) unsigned short Pl[16][32];

  const unsigned short* qp = Qb + (((size_t)(q0 + n) * 64 + h) * 64 + g * 8);
  bf16x8 qf0 = *(const bf16x8*)qp;
  bf16x8 qf1 = *(const bf16x8*)(qp + 32);

  const int q_lane = q0 + n;
  int k_lo = q0 - 127; if (k_lo < 0) k_lo = 0;
  k_lo &= ~31;
  const int k_end = q0 + 16;

  float m = -3.0e38f, lsum = 0.0f;
  f32x4 oacc[4] = {};

  for (int kk = k_lo; kk < k_end; kk += 32) {
    int kr0 = kk + n;      if (kr0 > 1023) kr0 = 1023;
    int kr1 = kk + 16 + n; if (kr1 > 1023) kr1 = 1023;
    const unsigned short* kp0 = Kb + (((size_t)kr0 * 8 + kvh) * 64 + g * 8);
    const unsigned short* kp1 = Kb + (((size_t)kr1 * 8 + kvh) * 64 + g * 8);
    bf16x8 ka0 = *(const bf16x8*)kp0;
    bf16x8 ka1 = *(const bf16x8*)(kp0 + 32);
    bf16x8 kb0 = *(const bf16x8*)kp1;
    bf16x8 kb1 = *(const bf16x8*)(kp1 + 32);
    f32x4 st0 = {}, st1 = {};
    st0 = __builtin_amdgcn_mfma_f32_16x16x32_bf16(ka0, qf0, st0, 0, 0, 0);
    st0 = __builtin_amdgcn_mfma_f32_16x16x32_bf16(ka1, qf1, st0, 0, 0, 0);
    st1 = __builtin_amdgcn_mfma_f32_16x16x32_bf16(kb0, qf0, st1, 0, 0, 0);
    st1 = __builtin_amdgcn_mfma_f32_16x16x32_bf16(kb1, qf1, st1, 0, 0, 0);

    float tm = -3.0e38f;
#pragma unroll
    for (int r = 0; r < 4; r++) {
      int k0i = kk + 4 * g + r;
      int k1i = k0i + 16;
      bool ok0 = (k0i <= q_lane) && (q_lane - k0i < 128);
      bool ok1 = (k1i <= q_lane) && (q_lane - k1i < 128);
      st0[r] = ok0 ? st0[r] : -3.0e38f;
      st1[r] = ok1 ? st1[r] : -3.0e38f;
      tm = fmaxf(tm, fmaxf(st0[r], st1[r]));
    }
    tm = fmaxf(tm, __shfl_xor(tm, 16));
    tm = fmaxf(tm, __shfl_xor(tm, 32));

    float mn = fmaxf(m, tm);
    float corr = __expf(m - mn);
    m = mn;
    float p0[4], p1[4], ps = 0.0f;
#pragma unroll
    for (int r = 0; r < 4; r++) {
      p0[r] = __expf(st0[r] - mn);
      p1[r] = __expf(st1[r] - mn);
      ps += p0[r] + p1[r];
    }
    ps += __shfl_xor(ps, 16);
    ps += __shfl_xor(ps, 32);
    lsum = lsum * corr + ps;

    ushort4 w0, w1;
    w0.x = f2bf(p0[0]); w0.y = f2bf(p0[1]); w0.z = f2bf(p0[2]); w0.w = f2bf(p0[3]);
    w1.x = f2bf(p1[0]); w1.y = f2bf(p1[1]); w1.z = f2bf(p1[2]); w1.w = f2bf(p1[3]);
    *(ushort4*)&Pl[n][4 * g]      = w0;
    *(ushort4*)&Pl[n][16 + 4 * g] = w1;
    __syncthreads();
    bf16x8 pf = *(const bf16x8*)&Pl[n][8 * g];
    __syncthreads();

#pragma unroll
    for (int db = 0; db < 4; db++) {
      const unsigned short* vp = Vt + ((size_t)(kvh * 64 + db * 16 + n)) * 1024 + kk + 8 * g;
      bf16x8 vf = *(const bf16x8*)vp;
#pragma unroll
      for (int r = 0; r < 4; r++) oacc[db][r] *= corr;
      oacc[db] = __builtin_amdgcn_mfma_f32_16x16x32_bf16(vf, pf, oacc[db], 0, 0, 0);
    }
  }

  float sink = sinks[h];
  float mn2 = fmaxf(m, sink);
  float corr2 = __expf(m - mn2);
  float denom = lsum * corr2 + __expf(sink - mn2);
  float fs = corr2 / denom;

#pragma unroll
  for (int db = 0; db < 4; db++) {
    ushort4 r;
    r.x = f2bf(oacc[db][0] * fs);
    r.y = f2bf(oacc[db][1] * fs);
    r.z = f2bf(oacc[db][2] * fs);
    r.w = f2bf(oacc[db][3] * fs);
    *(ushort4*)(out + (size_t)q_lane * 4096 + h * 64 + db * 16 + 4 * g) = r;
  }
}

extern "C" void kernel_launch(void* const* d_in, const int* in_sizes, int n_in,
                              void* d_out, int out_size, void* d_ws, size_t ws_size,
                              hipStream_t stream) {
  const float* x = (const float*)d_in[0];
  const int* positions = (const int*)d_in[1];
  const float* Wq = (const float*)d_in[2];
  const float* bq = (const float*)d_in[3];
  const float* Wk = (const float*)d_in[4];
  const float* bk = (const float*)d_in[5];
  const float* Wv = (const float*)d_in[6];
  const float* bv = (const float*)d_in[7];
  const float* Wo = (const float*)d_in[8];
  const float* bo = (const float*)d_in[9];
  const float* sinks = (const float*)d_in[10];
  float* out = (float*)d_out;

  char* ws = (char*)d_ws;
  unsigned short* xb   = (unsigned short*)(ws + 0);          // 1024x2880 bf16
  unsigned short* wqkv = (unsigned short*)(ws + 5898240);    // 5120x2880 bf16
  unsigned short* wo   = (unsigned short*)(ws + 35389440);   // 2880x4096 bf16
  float* bqkv          = (float*)(ws + 58982400);            // 5120 f32
  float* cosT          = (float*)(ws + 59002880);            // 1024x32 f32
  float* sinT          = (float*)(ws + 59133952);            // 1024x32 f32
  const size_t SH = 59265024;                                // shared region
  unsigned short* qkv_part = (unsigned short*)(ws + SH);
  unsigned short* out_part = (unsigned short*)(ws + SH);            // split_o x 5,898,240
  unsigned short* attnb    = (unsigned short*)(ws + SH + 23592960); // 8,388,608
  const size_t TL = SH + 41943040;
  unsigned short* Qb = (unsigned short*)(ws + TL);                  // 8,388,608
  unsigned short* Kb = (unsigned short*)(ws + TL + 8388608);        // 1,048,576
  unsigned short* Vt = (unsigned short*)(ws + TL + 9437184);        // 1,048,576 + slack

  int split_q = 4, split_o = 4;
  if (ws_size < TL + 10485888) {
    split_q = 2; split_o = 2;
    attnb = (unsigned short*)(ws + SH + 11796480);
    Qb = (unsigned short*)(ws + SH + 20971520);
    Kb = Qb + 4194304;
    Vt = Kb + 524288;
  }

  const double TWO_PI = 6.283185307179586;
  double lowd = 64.0 * log(4096.0 / (32.0 * TWO_PI)) / (2.0 * log(150000.0));
  if (lowd < 0.0) lowd = 0.0;
  double highd = 64.0 * log(4096.0 / (1.0 * TWO_PI)) / (2.0 * log(150000.0));
  if (highd > 31.0) highd = 31.0;
  if (lowd == highd) highd += 0.001;
  float mscale = (float)(0.1 * log(32.0) + 1.0);

  // 1. all converts + bias + rope tables (one launch)
  prep_all<<<28837, 256, 0, stream>>>(x, Wq, Wk, Wv, Wo, bq, bk, bv, positions,
                                      xb, wqkv, wo, bqkv, cosT, sinT,
                                      (float)lowd, (float)highd, mscale);

  // 2. QKV projection: split-K bf16 partials (XCD-swizzled grid)
  {
    int NT = 40, C = NT * split_q;
    int grid = 64 * ((C + 7) / 8);
    gemm_bt_sk<<<grid, 256, 0, stream>>>(xb, wqkv, qkv_part, 1024, 5120, 2880, NT, split_q);
  }

  // 3. fused reduce+rope (Q,K) and reduce+transpose (V)
  rope_vtrans<<<9280, 256, 0, stream>>>(qkv_part, bqkv, cosT, sinT, Qb, Kb, Vt, split_q);

  // 4. attention
  attn_mfma<<<dim3(64, 64), 64, 0, stream>>>(Qb, Kb, Vt, sinks, attnb);

  // 5. output projection: split-K bf16 partials
  {
    int NT = 23, C = NT * split_o;
    int grid = 64 * ((C + 7) / 8);
    gemm_bt_sk<<<grid, 256, 0, stream>>>(attnb, wo, out_part, 1024, 2880, 4096, NT, split_o);
  }

  // 6. final reduce + bias -> fp32
  reduce_f32<<<1440, 256, 0, stream>>>(out_part, bo, out, split_o);
}

// Round 6
// 306.291 us; speedup vs baseline: 1.5935x; 1.0384x over previous
//
#include <hip/hip_runtime.h>
#include <math.h>

#define S_LEN 1024
#define QKV_N 5120

typedef __attribute__((ext_vector_type(8))) __bf16 bf16x8;
typedef __attribute__((ext_vector_type(4))) float f32x4;

__device__ __forceinline__ unsigned short f2bf(float f) {
  unsigned int u = __float_as_uint(f);
  u += 0x7fff + ((u >> 16) & 1);
  return (unsigned short)(u >> 16);
}
__device__ __forceinline__ float bf2f(unsigned short u) {
  return __uint_as_float((unsigned int)u << 16);
}

__device__ __forceinline__ void async_copy16(const void* g, void* l) {
  __builtin_amdgcn_global_load_lds(
      (const __attribute__((address_space(1))) unsigned int*)g,
      (__attribute__((address_space(3))) unsigned int*)l, 16, 0, 0);
}

// ---------------- mega-fused prep: all cvt + bias concat + YaRN tables ----------------
__global__ void prep_all(const float* __restrict__ x, const float* __restrict__ Wq,
                         const float* __restrict__ Wk, const float* __restrict__ Wv,
                         const float* __restrict__ Wo, const float* __restrict__ bq,
                         const float* __restrict__ bk, const float* __restrict__ bv,
                         const int* __restrict__ positions,
                         unsigned short* __restrict__ xb, unsigned short* __restrict__ wqkv,
                         unsigned short* __restrict__ wo, float* __restrict__ bqkv,
                         float* __restrict__ cosT, float* __restrict__ sinT,
                         float low, float high, float mscale) {
  int i = blockIdx.x * 256 + threadIdx.x;
  if (i < 7372800) {
    const float* src;
    unsigned short* dst;
    int off;
    if (i < 737280)       { src = x;  dst = xb;                          off = i; }
    else if (i < 3686400) { src = Wq; dst = wqkv;                        off = i - 737280; }
    else if (i < 4055040) { src = Wk; dst = wqkv + (size_t)4096 * 2880;  off = i - 3686400; }
    else if (i < 4423680) { src = Wv; dst = wqkv + (size_t)4608 * 2880;  off = i - 4055040; }
    else                  { src = Wo; dst = wo;                          off = i - 4423680; }
    float4 v = ((const float4*)src)[off];
    ushort4 r;
    r.x = f2bf(v.x); r.y = f2bf(v.y); r.z = f2bf(v.z); r.w = f2bf(v.w);
    ((ushort4*)dst)[off] = r;
  } else if (i < 7374080) {
    int b = i - 7372800;
    int c0 = b * 4;
    float4 v;
    if (c0 < 4096)      v = ((const float4*)bq)[b];
    else if (c0 < 4608) v = ((const float4*)bk)[b - 1024];
    else                v = ((const float4*)bv)[b - 1152];
    ((float4*)bqkv)[b] = v;
  } else if (i < 7382272) {
    int tid = i - 7374080;         // 0..8191
    int s = tid >> 3;
    int j0 = (tid & 7) * 4;
    float pos = (float)positions[s];
    float4 cv, sv;
    float* cc = (float*)&cv;
    float* ss = (float*)&sv;
#pragma unroll
    for (int e = 0; e < 4; e++) {
      int j = j0 + e;
      float pf = powf(150000.0f, (float)j / 32.0f);
      float ramp = ((float)j - low) / (high - low);
      ramp = fminf(fmaxf(ramp, 0.0f), 1.0f);
      float invf = (1.0f / (32.0f * pf)) * ramp + (1.0f / pf) * (1.0f - ramp);
      float ang = pos * invf;
      cc[e] = cosf(ang) * mscale;
      ss[e] = sinf(ang) * mscale;
    }
    ((float4*)cosT)[s * 8 + (tid & 7)] = cv;
    ((float4*)sinT)[s * 8 + (tid & 7)] = sv;
  }
}

// ---------------- fused: (reduce+rope Q,K) | (reduce+transpose V) ----------------
__global__ __launch_bounds__(256) void rope_vtrans(
    const unsigned short* __restrict__ part, const float* __restrict__ bqkv,
    const float* __restrict__ cosT, const float* __restrict__ sinT,
    unsigned short* __restrict__ Qb, unsigned short* __restrict__ Kb,
    unsigned short* __restrict__ Vt, int SP) {
  const int bx = blockIdx.x;
  const int t = threadIdx.x;
  __shared__ unsigned short tile[128][66];
  if (bx < 9216) {
    int idx = bx * 256 + t;  // S*72*32
    int j = idx & 31;
    int hh = (idx >> 5) % 72;
    int s = idx / (72 * 32);
    int c1 = hh * 64 + j, c2 = c1 + 32;
    float xv = bqkv[c1], yv = bqkv[c2];
    for (int sp = 0; sp < SP; sp++) {
      const unsigned short* P = part + (size_t)sp * S_LEN * QKV_N + (size_t)s * QKV_N;
      xv += bf2f(P[c1]);
      yv += bf2f(P[c2]);
    }
    float c = cosT[s * 32 + j], sn = sinT[s * 32 + j];
    float o1 = xv * c - yv * sn;
    float o2 = yv * c + xv * sn;
    if (hh < 64) {
      unsigned short* q = Qb + ((size_t)s * 64 + hh) * 64;
      q[j]      = f2bf(o1 * 0.125f);   // fold in D^-0.5
      q[j + 32] = f2bf(o2 * 0.125f);
    } else {
      unsigned short* k = Kb + ((size_t)s * 8 + (hh - 64)) * 64;
      k[j]      = f2bf(o1);
      k[j + 32] = f2bf(o2);
    }
  } else {
    const int b = bx - 9216;
    const int kvh = b >> 3, s0 = (b & 7) * 128;
#pragma unroll
    for (int i = 0; i < 32; i++) {
      int e = t + i * 256;
      int s = e >> 6, d = e & 63;
      int col = 4608 + kvh * 64 + d;
      float v = bqkv[col];
      for (int sp = 0; sp < SP; sp++)
        v += bf2f(part[(size_t)sp * S_LEN * QKV_N + (size_t)(s0 + s) * QKV_N + col]);
      tile[s][d] = f2bf(v);
    }
    __syncthreads();
#pragma unroll
    for (int i = 0; i < 32; i++) {
      int e = t + i * 256;
      int d = e >> 7, s = e & 127;
      Vt[((size_t)kvh * 64 + d) * 1024 + s0 + s] = tile[s][d];
    }
  }
}

// ---------------- NT bf16 MFMA GEMM, BK=64, XOR-bank-swizzled LDS, split-K ----------------
// LDS layout: element (row, kgroup) lives at slot row*64 + (kgroup ^ (row&7))*8.
// Staging keeps the DMA-required contiguous lane->LDS map and permutes the GLOBAL
// k-group per lane instead. Read-side bank group = ((h*4+lq)^(row&7)) -> each of 8
// groups hit exactly 2x per 16 rows => 2-way (free, m136).
__global__ __launch_bounds__(256) void gemm_bt_sk(
    const unsigned short* __restrict__ A, const unsigned short* __restrict__ B,
    unsigned short* __restrict__ part, int M, int N, int K, int NT, int SP) {
  __shared__ __align__(16) unsigned short As[128 * 64];
  __shared__ __align__(16) unsigned short Bs[128 * 64];
  const int lb = blockIdx.x;
  const int aI = lb >> 6;
  const int rem = lb & 63;
  const int mI = rem >> 3;
  const int bI = rem & 7;
  const int c = aI * 8 + bI;
  if (c >= NT * SP) return;
  const int sI = c / NT, nI = c % NT;
  const int m0 = mI * 128, n0 = nI * 128;

  const int t = threadIdx.x;
  const int l = t & 63;
  const int w = t >> 6;
  const int lr = l & 15, lq = l >> 4;
  const int wm = (w >> 1) * 64, wn = (w & 1) * 64;

  const int T = K >> 6;                 // 64-wide k-iters
  const int kb = ((sI * T) / SP) * 64;
  const int ke = (((sI + 1) * T) / SP) * 64;

  // staging descriptors: 4 slots each for A and B
  const unsigned short* gA[4];
  const unsigned short* gB[4];
  unsigned short* lA[4];
  unsigned short* lB[4];
#pragma unroll
  for (int q = 0; q < 4; q++) {
    int s = q * 256 + t;            // LDS slot 0..1023
    int row = s >> 3;               // 0..127
    int kgX = s & 7;
    int kg = kgX ^ (row & 7);       // global k-group this lane fetches
    gA[q] = A + (size_t)(m0 + row) * K + kg * 8;
    int rb = n0 + row; if (rb > N - 1) rb = N - 1;
    gB[q] = B + (size_t)rb * K + kg * 8;
    lA[q] = &As[s * 8];
    lB[q] = &Bs[s * 8];
  }

  f32x4 acc[4][4] = {};

  for (int k0 = kb; k0 < ke; k0 += 64) {
#pragma unroll
    for (int q = 0; q < 4; q++) async_copy16(gA[q] + k0, lA[q]);
#pragma unroll
    for (int q = 0; q < 4; q++) async_copy16(gB[q] + k0, lB[q]);
    __syncthreads();
#pragma unroll
    for (int h = 0; h < 2; h++) {
      bf16x8 af[4], bf[4];
#pragma unroll
      for (int i = 0; i < 4; i++) {
        int row = wm + i * 16 + lr;
        af[i] = *(const bf16x8*)&As[row * 64 + (((h << 2) | lq) ^ (row & 7)) * 8];
      }
#pragma unroll
      for (int i = 0; i < 4; i++) {
        int row = wn + i * 16 + lr;
        bf[i] = *(const bf16x8*)&Bs[row * 64 + (((h << 2) | lq) ^ (row & 7)) * 8];
      }
#pragma unroll
      for (int mi = 0; mi < 4; mi++)
#pragma unroll
        for (int ni = 0; ni < 4; ni++)
          acc[mi][ni] = __builtin_amdgcn_mfma_f32_16x16x32_bf16(af[mi], bf[ni], acc[mi][ni], 0, 0, 0);
    }
    __syncthreads();
  }

  unsigned short* P = part + (size_t)sI * M * N;
#pragma unroll
  for (int mi = 0; mi < 4; mi++) {
#pragma unroll
    for (int ni = 0; ni < 4; ni++) {
      int col = n0 + wn + ni * 16 + lr;
      if (col < N) {
#pragma unroll
        for (int r = 0; r < 4; r++) {
          int row = m0 + wm + mi * 16 + lq * 4 + r;
          P[(size_t)row * N + col] = f2bf(acc[mi][ni][r]);
        }
      }
    }
  }
}

// ---------------- split-K reduce: sum bf16 partials + bias -> fp32 out ----------------
__global__ void reduce_f32(const unsigned short* __restrict__ part, const float* __restrict__ bias,
                           float* __restrict__ out, int SP) {
  int i = blockIdx.x * 256 + threadIdx.x;  // 0..368639 (8-elem chunks of 1024x2880)
  if (i >= 368640) return;
  float acc[8];
  int bc = (i % 360) * 8;
#pragma unroll
  for (int e = 0; e < 8; e++) acc[e] = bias[bc + e];
  for (int sp = 0; sp < SP; sp++) {
    const ushort4* P = (const ushort4*)(part + (size_t)sp * 2949120);
    ushort4 u0 = P[i * 2], u1 = P[i * 2 + 1];
    acc[0] += bf2f(u0.x); acc[1] += bf2f(u0.y); acc[2] += bf2f(u0.z); acc[3] += bf2f(u0.w);
    acc[4] += bf2f(u1.x); acc[5] += bf2f(u1.y); acc[6] += bf2f(u1.z); acc[7] += bf2f(u1.w);
  }
  float4 o0 = {acc[0], acc[1], acc[2], acc[3]};
  float4 o1 = {acc[4], acc[5], acc[6], acc[7]};
  ((float4*)out)[i * 2] = o0;
  ((float4*)out)[i * 2 + 1] = o1;
}

// ---------------- MFMA flash attention, sliding window + sinks ----------------
__global__ __launch_bounds__(64) void attn_mfma(
    const unsigned short* __restrict__ Qb,   // [S][H][64] bf16 (pre-scaled)
    const unsigned short* __restrict__ Kb,   // [S][KV][64] bf16
    const unsigned short* __restrict__ Vt,   // [KV*64][S] bf16 (+slack)
    const float* __restrict__ sinks,
    unsigned short* __restrict__ out) {      // [S][4096] bf16
  const int h = blockIdx.x;
  const int q0 = blockIdx.y * 16;
  const int kvh = h >> 3;
  const int l = threadIdx.x;
  const int n = l & 15;
  const int g = l >> 4;

  __shared__ __align__(16) unsigned short Pl[16][32];

  const unsigned short* qp = Qb + (((size_t)(q0 + n) * 64 + h) * 64 + g * 8);
  bf16x8 qf0 = *(const bf16x8*)qp;
  bf16x8 qf1 = *(const bf16x8*)(qp + 32);

  const int q_lane = q0 + n;
  int k_lo = q0 - 127; if (k_lo < 0) k_lo = 0;
  k_lo &= ~31;
  const int k_end = q0 + 16;

  float m = -3.0e38f, lsum = 0.0f;
  f32x4 oacc[4] = {};

  for (int kk = k_lo; kk < k_end; kk += 32) {
    int kr0 = kk + n;      if (kr0 > 1023) kr0 = 1023;
    int kr1 = kk + 16 + n; if (kr1 > 1023) kr1 = 1023;
    const unsigned short* kp0 = Kb + (((size_t)kr0 * 8 + kvh) * 64 + g * 8);
    const unsigned short* kp1 = Kb + (((size_t)kr1 * 8 + kvh) * 64 + g * 8);
    bf16x8 ka0 = *(const bf16x8*)kp0;
    bf16x8 ka1 = *(const bf16x8*)(kp0 + 32);
    bf16x8 kb0 = *(const bf16x8*)kp1;
    bf16x8 kb1 = *(const bf16x8*)(kp1 + 32);
    f32x4 st0 = {}, st1 = {};
    st0 = __builtin_amdgcn_mfma_f32_16x16x32_bf16(ka0, qf0, st0, 0, 0, 0);
    st0 = __builtin_amdgcn_mfma_f32_16x16x32_bf16(ka1, qf1, st0, 0, 0, 0);
    st1 = __builtin_amdgcn_mfma_f32_16x16x32_bf16(kb0, qf0, st1, 0, 0, 0);
    st1 = __builtin_amdgcn_mfma_f32_16x16x32_bf16(kb1, qf1, st1, 0, 0, 0);

    float tm = -3.0e38f;
#pragma unroll
    for (int r = 0; r < 4; r++) {
      int k0i = kk + 4 * g + r;
      int k1i = k0i + 16;
      bool ok0 = (k0i <= q_lane) && (q_lane - k0i < 128);
      bool ok1 = (k1i <= q_lane) && (q_lane - k1i < 128);
      st0[r] = ok0 ? st0[r] : -3.0e38f;
      st1[r] = ok1 ? st1[r] : -3.0e38f;
      tm = fmaxf(tm, fmaxf(st0[r], st1[r]));
    }
    tm = fmaxf(tm, __shfl_xor(tm, 16));
    tm = fmaxf(tm, __shfl_xor(tm, 32));

    float mn = fmaxf(m, tm);
    float corr = __expf(m - mn);
    m = mn;
    float p0[4], p1[4], ps = 0.0f;
#pragma unroll
    for (int r = 0; r < 4; r++) {
      p0[r] = __expf(st0[r] - mn);
      p1[r] = __expf(st1[r] - mn);
      ps += p0[r] + p1[r];
    }
    ps += __shfl_xor(ps, 16);
    ps += __shfl_xor(ps, 32);
    lsum = lsum * corr + ps;

    ushort4 w0, w1;
    w0.x = f2bf(p0[0]); w0.y = f2bf(p0[1]); w0.z = f2bf(p0[2]); w0.w = f2bf(p0[3]);
    w1.x = f2bf(p1[0]); w1.y = f2bf(p1[1]); w1.z = f2bf(p1[2]); w1.w = f2bf(p1[3]);
    *(ushort4*)&Pl[n][4 * g]      = w0;
    *(ushort4*)&Pl[n][16 + 4 * g] = w1;
    __syncthreads();
    bf16x8 pf = *(const bf16x8*)&Pl[n][8 * g];
    __syncthreads();

#pragma unroll
    for (int db = 0; db < 4; db++) {
      const unsigned short* vp = Vt + ((size_t)(kvh * 64 + db * 16 + n)) * 1024 + kk + 8 * g;
      bf16x8 vf = *(const bf16x8*)vp;
#pragma unroll
      for (int r = 0; r < 4; r++) oacc[db][r] *= corr;
      oacc[db] = __builtin_amdgcn_mfma_f32_16x16x32_bf16(vf, pf, oacc[db], 0, 0, 0);
    }
  }

  float sink = sinks[h];
  float mn2 = fmaxf(m, sink);
  float corr2 = __expf(m - mn2);
  float denom = lsum * corr2 + __expf(sink - mn2);
  float fs = corr2 / denom;

#pragma unroll
  for (int db = 0; db < 4; db++) {
    ushort4 r;
    r.x = f2bf(oacc[db][0] * fs);
    r.y = f2bf(oacc[db][1] * fs);
    r.z = f2bf(oacc[db][2] * fs);
    r.w = f2bf(oacc[db][3] * fs);
    *(ushort4*)(out + (size_t)q_lane * 4096 + h * 64 + db * 16 + 4 * g) = r;
  }
}

extern "C" void kernel_launch(void* const* d_in, const int* in_sizes, int n_in,
                              void* d_out, int out_size, void* d_ws, size_t ws_size,
                              hipStream_t stream) {
  const float* x = (const float*)d_in[0];
  const int* positions = (const int*)d_in[1];
  const float* Wq = (const float*)d_in[2];
  const float* bq = (const float*)d_in[3];
  const float* Wk = (const float*)d_in[4];
  const float* bk = (const float*)d_in[5];
  const float* Wv = (const float*)d_in[6];
  const float* bv = (const float*)d_in[7];
  const float* Wo = (const float*)d_in[8];
  const float* bo = (const float*)d_in[9];
  const float* sinks = (const float*)d_in[10];
  float* out = (float*)d_out;

  char* ws = (char*)d_ws;
  unsigned short* xb   = (unsigned short*)(ws + 0);          // 1024x2880 bf16
  unsigned short* wqkv = (unsigned short*)(ws + 5898240);    // 5120x2880 bf16
  unsigned short* wo   = (unsigned short*)(ws + 35389440);   // 2880x4096 bf16
  float* bqkv          = (float*)(ws + 58982400);            // 5120 f32
  float* cosT          = (float*)(ws + 59002880);            // 1024x32 f32
  float* sinT          = (float*)(ws + 59133952);            // 1024x32 f32
  const size_t SH = 59265024;                                // shared region
  unsigned short* qkv_part = (unsigned short*)(ws + SH);
  unsigned short* out_part = (unsigned short*)(ws + SH);            // split_o x 5,898,240
  unsigned short* attnb    = (unsigned short*)(ws + SH + 23592960); // 8,388,608
  const size_t TL = SH + 41943040;
  unsigned short* Qb = (unsigned short*)(ws + TL);                  // 8,388,608
  unsigned short* Kb = (unsigned short*)(ws + TL + 8388608);        // 1,048,576
  unsigned short* Vt = (unsigned short*)(ws + TL + 9437184);        // 1,048,576 + slack

  int split_q = 4, split_o = 4;
  if (ws_size < TL + 10485888) {
    split_q = 2; split_o = 2;
    attnb = (unsigned short*)(ws + SH + 11796480);
    Qb = (unsigned short*)(ws + SH + 20971520);
    Kb = Qb + 4194304;
    Vt = Kb + 524288;
  }

  const double TWO_PI = 6.283185307179586;
  double lowd = 64.0 * log(4096.0 / (32.0 * TWO_PI)) / (2.0 * log(150000.0));
  if (lowd < 0.0) lowd = 0.0;
  double highd = 64.0 * log(4096.0 / (1.0 * TWO_PI)) / (2.0 * log(150000.0));
  if (highd > 31.0) highd = 31.0;
  if (lowd == highd) highd += 0.001;
  float mscale = (float)(0.1 * log(32.0) + 1.0);

  // 1. all converts + bias + rope tables (one launch)
  prep_all<<<28837, 256, 0, stream>>>(x, Wq, Wk, Wv, Wo, bq, bk, bv, positions,
                                      xb, wqkv, wo, bqkv, cosT, sinT,
                                      (float)lowd, (float)highd, mscale);

  // 2. QKV projection: split-K bf16 partials (XCD-swizzled grid, BK=64)
  {
    int NT = 40, C = NT * split_q;
    int grid = 64 * ((C + 7) / 8);
    gemm_bt_sk<<<grid, 256, 0, stream>>>(xb, wqkv, qkv_part, 1024, 5120, 2880, NT, split_q);
  }

  // 3. fused reduce+rope (Q,K) and reduce+transpose (V)
  rope_vtrans<<<9280, 256, 0, stream>>>(qkv_part, bqkv, cosT, sinT, Qb, Kb, Vt, split_q);

  // 4. attention
  attn_mfma<<<dim3(64, 64), 64, 0, stream>>>(Qb, Kb, Vt, sinks, attnb);

  // 5. output projection: split-K bf16 partials (BK=64)
  {
    int NT = 23, C = NT * split_o;
    int grid = 64 * ((C + 7) / 8);
    gemm_bt_sk<<<grid, 256, 0, stream>>>(attnb, wo, out_part, 1024, 2880, 4096, NT, split_o);
  }

  // 6. final reduce + bias -> fp32
  reduce_f32<<<1440, 256, 0, stream>>>(out_part, bo, out, split_o);
}